// Round 5
// baseline (520.767 us; speedup 1.0000x reference)
//
#include <hip/hip_runtime.h>
#include <hip/hip_bf16.h>

#define B_ 4
#define T_ 3
#define M_ 4096
#define C_ 768
#define H_ 12
#define K_ 256
#define HD_ 64
#define TM_ 4099      // T_ + M_
#define SCALE_ 0.125f // HD^-0.5
#define NBLK_ 144     // B*H*T, blk = b*36 + h*3 + t

// order-preserving float->uint key (larger float -> larger key)
__device__ __forceinline__ unsigned keyf(float f) {
  unsigned u = __float_as_uint(f);
  return (u & 0x80000000u) ? ~u : (u | 0x80000000u);
}

__device__ __forceinline__ int block_excl_scan256(int v, int tid, int* sbuf) {
  sbuf[tid] = v;
  __syncthreads();
  #pragma unroll
  for (int off = 1; off < 256; off <<= 1) {
    int add = (tid >= off) ? sbuf[tid - off] : 0;
    __syncthreads();
    sbuf[tid] += add;
    __syncthreads();
  }
  int inc = sbuf[tid];
  __syncthreads();
  return inc - v;
}

// ---------- kernels ----------
__global__ void zero_out_kernel(float4* __restrict__ out, int n4) {
  int i = blockIdx.x * 256 + threadIdx.x;
  if (i < n4) out[i] = make_float4(0.f, 0.f, 0.f, 0.f);
}

// q[b,t,d] = sum_c x[b,t,c] * Wq[t,d,c] + bq[t,d]
// grid = (T, 12 dchunks of 64), block = 256. Reads Wq once (4 b per block).
__global__ __launch_bounds__(256) void q_kernel(const float* __restrict__ x,
                                                const float* __restrict__ Wq,
                                                const float* __restrict__ bq,
                                                float* __restrict__ qbuf) {
  int t = blockIdx.x;
  int d0 = blockIdx.y * 64;
  int tid = threadIdx.x;
  __shared__ float ar[B_][C_];
  for (int i = tid; i < B_ * C_; i += 256) {
    int bb = i / C_, c = i % C_;
    ar[bb][c] = x[((size_t)(bb * TM_ + t)) * C_ + c];
  }
  __syncthreads();
  int grp = tid >> 4, ln = tid & 15;
  #pragma unroll
  for (int j = 0; j < 4; ++j) {
    int d = d0 + grp * 4 + j;
    const float4* wr = (const float4*)(Wq + ((size_t)t * C_ + d) * C_);
    float a0 = 0.f, a1 = 0.f, a2 = 0.f, a3 = 0.f;
    #pragma unroll
    for (int it = 0; it < 12; ++it) {
      float4 w4 = wr[ln + 16 * it];
      const float4 x0 = *(const float4*)&ar[0][(ln + 16 * it) * 4];
      const float4 x1 = *(const float4*)&ar[1][(ln + 16 * it) * 4];
      const float4 x2 = *(const float4*)&ar[2][(ln + 16 * it) * 4];
      const float4 x3 = *(const float4*)&ar[3][(ln + 16 * it) * 4];
      a0 += w4.x * x0.x + w4.y * x0.y + w4.z * x0.z + w4.w * x0.w;
      a1 += w4.x * x1.x + w4.y * x1.y + w4.z * x1.z + w4.w * x1.w;
      a2 += w4.x * x2.x + w4.y * x2.y + w4.z * x2.z + w4.w * x2.w;
      a3 += w4.x * x3.x + w4.y * x3.y + w4.z * x3.z + w4.w * x3.w;
    }
    #pragma unroll
    for (int off = 1; off < 16; off <<= 1) {
      a0 += __shfl_xor(a0, off, 16);
      a1 += __shfl_xor(a1, off, 16);
      a2 += __shfl_xor(a2, off, 16);
      a3 += __shfl_xor(a3, off, 16);
    }
    if (ln == 0) {
      float bqv = bq[t * C_ + d];
      qbuf[(size_t)(0 * T_ + t) * C_ + d] = a0 + bqv;
      qbuf[(size_t)(1 * T_ + t) * C_ + d] = a1 + bqv;
      qbuf[(size_t)(2 * T_ + t) * C_ + d] = a2 + bqv;
      qbuf[(size_t)(3 * T_ + t) * C_ + d] = a3 + bqv;
    }
  }
}

// sprj[blk, c] = sum_{j<64} q[b,t,h*64+j] * Wkv[h*64+j, c]
// qbb[blk]    = sum_{j<64} q[b,t,h*64+j] * bkv[h*64+j]
__global__ __launch_bounds__(256) void sprj_kernel(const float* __restrict__ qbuf,
                                                   const float* __restrict__ Wkv,
                                                   const float* __restrict__ bkv,
                                                   float* __restrict__ sprj,
                                                   float* __restrict__ qbb) {
  int blk = blockIdx.x;
  int t = blk % T_;
  int h = (blk / T_) % H_;
  int b = blk / (T_ * H_);
  int tid = threadIdx.x;
  __shared__ float qs[HD_];
  if (tid < HD_) qs[tid] = qbuf[((size_t)(b * T_ + t)) * C_ + h * HD_ + tid];
  __syncthreads();
  if (tid == 0) {
    float s = 0.f;
    for (int j = 0; j < HD_; ++j) s += qs[j] * bkv[h * HD_ + j];
    qbb[blk] = s;
  }
  float a0 = 0.f, a1 = 0.f, a2 = 0.f;
  for (int j = 0; j < HD_; ++j) {
    const float* wr = Wkv + ((size_t)(h * HD_ + j)) * C_;
    float qj = qs[j];
    a0 += qj * wr[tid];
    a1 += qj * wr[tid + 256];
    a2 += qj * wr[tid + 512];
  }
  float* sp = sprj + (size_t)blk * C_;
  sp[tid] = a0;
  sp[tid + 256] = a1;
  sp[tid + 512] = a2;
}

// scores as LDS-tiled GEMM: scg[b*36+j][m] = (sprj[j,:].feat[b,m,:] + qbb)*SCALE
// grid = (B, M/64), block = 128. Thread: 2 m x 9 blk register tile.
__global__ __launch_bounds__(128) void score_kernel(const float* __restrict__ x,
                                                    const float* __restrict__ sprj,
                                                    const float* __restrict__ qbb,
                                                    float* __restrict__ scg) {
  int b = blockIdx.x;
  int m0 = blockIdx.y * 64;
  int tid = threadIdx.x;
  int ml = tid & 31, g = tid >> 5; // g in 0..3, 9 blks each

  __shared__ float fl[64][64]; // [k][m] (transposed feat chunk)
  __shared__ float sl[36][64]; // [j][k]

  float acc0[9], acc1[9];
  #pragma unroll
  for (int j = 0; j < 9; ++j) { acc0[j] = 0.f; acc1[j] = 0.f; }

  const float* fbase = x + ((size_t)b * TM_ + T_ + m0) * C_;
  const float* sbase = sprj + (size_t)b * 36 * C_;

  int r = tid >> 1, half = tid & 1;
  for (int kc = 0; kc < 12; ++kc) {
    // stage feat chunk transposed: fl[c][r] = feat[m0+r][kc*64+c]
    const float* frow = fbase + (size_t)r * C_ + kc * 64 + half * 32;
    #pragma unroll
    for (int j4 = 0; j4 < 8; ++j4) {
      float4 f4 = *(const float4*)(frow + j4 * 4);
      int c = half * 32 + j4 * 4;
      fl[c + 0][r] = f4.x;
      fl[c + 1][r] = f4.y;
      fl[c + 2][r] = f4.z;
      fl[c + 3][r] = f4.w;
    }
    // stage sprj chunk
    for (int i = tid; i < 36 * 64; i += 128) {
      int row = i >> 6, col = i & 63;
      sl[row][col] = sbase[(size_t)row * C_ + kc * 64 + col];
    }
    __syncthreads();
    #pragma unroll 4
    for (int k = 0; k < 64; ++k) {
      float2 f = *(const float2*)&fl[k][2 * ml];
      #pragma unroll
      for (int j = 0; j < 9; ++j) {
        float s = sl[g * 9 + j][k];
        acc0[j] += f.x * s;
        acc1[j] += f.y * s;
      }
    }
    __syncthreads();
  }
  #pragma unroll
  for (int j = 0; j < 9; ++j) {
    int blk = b * 36 + g * 9 + j;
    float qb = qbb[blk];
    float2 o;
    o.x = (acc0[j] + qb) * SCALE_;
    o.y = (acc1[j] + qb) * SCALE_;
    *(float2*)&scg[(size_t)blk * M_ + m0 + 2 * ml] = o;
  }
}

// Per blk: exact top-K via radix select (index-ordered ties, = lax.top_k),
// softmax over selected; writes ibuf/wbuf. grid = 144, block = 256.
__global__ __launch_bounds__(256) void topk_kernel(const float* __restrict__ scg,
                                                   int* __restrict__ ibuf,
                                                   float* __restrict__ wbuf) {
  int blk = blockIdx.x;
  int tid = threadIdx.x;

  __shared__ float sc[M_];
  __shared__ unsigned hist[256];
  __shared__ int sbuf[256];
  __shared__ int selm[K_];
  __shared__ float red[256];
  __shared__ int sh_bin, sh_rem;

  const float4* srow = (const float4*)(scg + (size_t)blk * M_);
  for (int i = tid; i < M_ / 4; i += 256) ((float4*)sc)[i] = srow[i];
  __syncthreads();

  // ---- radix select: find K-th largest key ----
  unsigned prefix = 0;
  int remaining = K_;
  for (int shift = 24; shift >= 0; shift -= 8) {
    hist[tid] = 0;
    __syncthreads();
    unsigned pmask = (shift == 24) ? 0u : (0xFFFFFFFFu << (shift + 8));
    #pragma unroll 4
    for (int i = 0; i < 16; ++i) {
      unsigned k = keyf(sc[tid * 16 + i]);
      if ((k & pmask) == prefix) atomicAdd(&hist[(k >> shift) & 255u], 1u);
    }
    __syncthreads();
    int bin = 255 - tid;
    int v = (int)hist[bin];
    int cex = block_excl_scan256(v, tid, sbuf);
    if (cex < remaining && cex + v >= remaining) {
      sh_bin = bin;
      sh_rem = remaining - cex;
    }
    __syncthreads();
    prefix |= ((unsigned)sh_bin) << shift;
    remaining = sh_rem;
    __syncthreads();
  }
  const unsigned tau = prefix;
  const int r = remaining;      // # of ==tau entries to keep (lowest indices)
  const int cgt = K_ - r;       // # of >tau entries

  // ---- compact selection in ascending-index order (deterministic) ----
  int base = tid * 16;
  int myCnt = 0, myTie = 0;
  #pragma unroll
  for (int i = 0; i < 16; i++) {
    unsigned k = keyf(sc[base + i]);
    myCnt += (k > tau);
    myTie += (k == tau);
  }
  int offs = block_excl_scan256(myCnt, tid, sbuf);
  int toffs = block_excl_scan256(myTie, tid, sbuf);
  for (int i = 0; i < 16; i++) {
    int m = base + i;
    unsigned k = keyf(sc[m]);
    if (k > tau) {
      selm[offs++] = m;
    } else if (k == tau) {
      if (toffs < r) selm[cgt + toffs] = m;
      toffs++;
    }
  }
  __syncthreads();

  // ---- softmax over the K selected ----
  int m = selm[tid];
  float val = sc[m];
  red[tid] = val;
  __syncthreads();
  for (int off = 128; off > 0; off >>= 1) {
    if (tid < off) red[tid] = fmaxf(red[tid], red[tid + off]);
    __syncthreads();
  }
  float mx = red[0];
  __syncthreads();
  float e = expf(val - mx);
  red[tid] = e;
  __syncthreads();
  for (int off = 128; off > 0; off >>= 1) {
    if (tid < off) red[tid] += red[tid + off];
    __syncthreads();
  }
  ibuf[(size_t)blk * K_ + tid] = m;
  wbuf[(size_t)blk * K_ + tid] = e / red[0];
}

// wfp[blk*4+kc][c] = sum_{k in chunk} w_k * feat[m_k, c]
// grid = (144, 4, 3 c-segments), block = 256
__global__ __launch_bounds__(256) void wfeat_kernel(const float* __restrict__ x,
                                                    const int* __restrict__ ibuf,
                                                    const float* __restrict__ wbuf,
                                                    float* __restrict__ wfp) {
  int blk = blockIdx.x, kc = blockIdx.y, cseg = blockIdx.z;
  int b = blk / 36;
  int tid = threadIdx.x;
  __shared__ int ml[64];
  __shared__ float wl[64];
  if (tid < 64) {
    ml[tid] = ibuf[(size_t)blk * K_ + kc * 64 + tid];
    wl[tid] = wbuf[(size_t)blk * K_ + kc * 64 + tid];
  }
  __syncthreads();
  int c = cseg * 256 + tid;
  const float* fbase = x + ((size_t)b * TM_ + T_) * C_ + c;
  float a = 0.f;
  #pragma unroll 4
  for (int kk = 0; kk < 64; ++kk) {
    a += wl[kk] * fbase[(size_t)ml[kk] * C_];
  }
  wfp[((size_t)blk * 4 + kc) * C_ + c] = a;
}

// attn_token[b,t,h*64+rr] = (sum_kc wfp) . Wv[row] + bv[row]; grid = 144
__global__ __launch_bounds__(256) void attn_token_kernel(
    const float* __restrict__ wfp, const float* __restrict__ Wkv,
    const float* __restrict__ bkv, float* __restrict__ atbuf) {
  int blk = blockIdx.x;
  int t = blk % T_;
  int h = (blk / T_) % H_;
  int b = blk / (T_ * H_);
  int tid = threadIdx.x;
  __shared__ float wfeat[C_];
  const float* p0 = wfp + ((size_t)blk * 4) * C_;
  #pragma unroll
  for (int j = 0; j < 3; ++j) {
    int c = tid + j * 256;
    wfeat[c] = p0[c] + p0[C_ + c] + p0[2 * C_ + c] + p0[3 * C_ + c];
  }
  __syncthreads();
  int grp = tid >> 4, ln = tid & 15;
  for (int rr = grp; rr < HD_; rr += 16) {
    const float4* wr = (const float4*)(Wkv + ((size_t)(C_ + h * HD_ + rr)) * C_);
    float acc = 0.f;
    #pragma unroll
    for (int it = 0; it < 12; ++it) {
      float4 wv = wr[ln + it * 16];
      const float4 fv = *(const float4*)&wfeat[(ln + it * 16) * 4];
      acc += wv.x * fv.x + wv.y * fv.y + wv.z * fv.z + wv.w * fv.w;
    }
    acc += __shfl_xor(acc, 1, 16);
    acc += __shfl_xor(acc, 2, 16);
    acc += __shfl_xor(acc, 4, 16);
    acc += __shfl_xor(acc, 8, 16);
    if (ln == 0)
      atbuf[((size_t)(b * T_ + t)) * C_ + h * HD_ + rr] =
          acc + bkv[C_ + h * HD_ + rr];
  }
}

// token_output[b,t,d] = sum_c attn_token[b,t,c] * Wexp[t,d,c]
// grid = (T, 12 dchunks of 64), block 256. Reads Wexp once (4 b per block).
__global__ __launch_bounds__(256) void token_out(const float* __restrict__ atbuf,
                                                 const float* __restrict__ Wexp,
                                                 float* __restrict__ out) {
  int t = blockIdx.x;
  int d0 = blockIdx.y * 64;
  int tid = threadIdx.x;
  __shared__ float ar[B_][C_];
  for (int i = tid; i < B_ * C_; i += 256) {
    int bb = i / C_, c = i % C_;
    ar[bb][c] = atbuf[((size_t)(bb * T_ + t)) * C_ + c];
  }
  __syncthreads();
  int grp = tid >> 4, ln = tid & 15;
  #pragma unroll
  for (int j = 0; j < 4; ++j) {
    int d = d0 + grp * 4 + j;
    const float4* wr = (const float4*)(Wexp + ((size_t)t * C_ + d) * C_);
    float a0 = 0.f, a1 = 0.f, a2 = 0.f, a3 = 0.f;
    #pragma unroll
    for (int it = 0; it < 12; ++it) {
      float4 w4 = wr[ln + 16 * it];
      const float4 x0 = *(const float4*)&ar[0][(ln + 16 * it) * 4];
      const float4 x1 = *(const float4*)&ar[1][(ln + 16 * it) * 4];
      const float4 x2 = *(const float4*)&ar[2][(ln + 16 * it) * 4];
      const float4 x3 = *(const float4*)&ar[3][(ln + 16 * it) * 4];
      a0 += w4.x * x0.x + w4.y * x0.y + w4.z * x0.z + w4.w * x0.w;
      a1 += w4.x * x1.x + w4.y * x1.y + w4.z * x1.z + w4.w * x1.w;
      a2 += w4.x * x2.x + w4.y * x2.y + w4.z * x2.z + w4.w * x2.w;
      a3 += w4.x * x3.x + w4.y * x3.y + w4.z * x3.z + w4.w * x3.w;
    }
    #pragma unroll
    for (int off = 1; off < 16; off <<= 1) {
      a0 += __shfl_xor(a0, off, 16);
      a1 += __shfl_xor(a1, off, 16);
      a2 += __shfl_xor(a2, off, 16);
      a3 += __shfl_xor(a3, off, 16);
    }
    if (ln == 0) {
      out[((size_t)0 * TM_ + t) * C_ + d] = a0;
      out[((size_t)1 * TM_ + t) * C_ + d] = a1;
      out[((size_t)2 * TM_ + t) * C_ + d] = a2;
      out[((size_t)3 * TM_ + t) * C_ + d] = a3;
    }
  }
}

// Sparse feature expansion as LDS-tiled GEMM.
// Per (b,h,t,kchunk,dtile): C[64 kk x 128 d] = fw[64x64] @ wt[64x128], then
// atomic-scatter rows to out[b, T+m_kk, d0..d0+127].
// grid = (576, 6), block = 256, LDS ~50.7KB (3 blocks/CU).
__global__ __launch_bounds__(256) void feature_scatter(
    const float* __restrict__ x, const float* __restrict__ Wexp,
    const int* __restrict__ ibuf, const float* __restrict__ wbuf,
    float* __restrict__ out) {
  int bht = blockIdx.x >> 2, ks = blockIdx.x & 3;
  int d0 = blockIdx.y << 7;
  int t = bht % T_;
  int h = (bht / T_) % H_;
  int b = bht / (T_ * H_);
  int tid = threadIdx.x;

  __shared__ float fw[64][65];  // [kk][c], w_k * feat
  __shared__ float wt[64][132]; // [c][d] transposed Wexp tile
  __shared__ int ml[64];

  const int* ip = ibuf + (size_t)bht * K_ + ks * 64;
  const float* wp = wbuf + (size_t)bht * K_ + ks * 64;
  if (tid < 64) ml[tid] = ip[tid];
  __syncthreads();

  // stage fw: thread (kk = tid>>2, cp = (tid&3)*16)
  {
    int kk = tid >> 2, cp = (tid & 3) * 16;
    float wv = wp[kk];
    const float* fr = x + ((size_t)(b * TM_) + T_ + ml[kk]) * C_ + h * HD_ + cp;
    #pragma unroll
    for (int j = 0; j < 16; j += 4) {
      float4 f = *(const float4*)(fr + j);
      fw[kk][cp + j + 0] = f.x * wv;
      fw[kk][cp + j + 1] = f.y * wv;
      fw[kk][cp + j + 2] = f.z * wv;
      fw[kk][cp + j + 3] = f.w * wv;
    }
  }
  // stage wt transposed, coalesced global reads (rows of Wexp)
  {
    const float* wbase = Wexp + ((size_t)t * C_ + d0) * C_ + h * HD_;
    #pragma unroll
    for (int l = 0; l < 8; ++l) {
      int f = l * 256 + tid;
      int d = f >> 4, c4 = (f & 15) * 4;
      float4 g = *(const float4*)(wbase + (size_t)d * C_ + c4);
      wt[c4 + 0][d] = g.x;
      wt[c4 + 1][d] = g.y;
      wt[c4 + 2][d] = g.z;
      wt[c4 + 3][d] = g.w;
    }
  }
  __syncthreads();

  int tkk = tid >> 4, tdd = tid & 15;
  int kk0 = tkk * 4;
  float acc[4][8];
  #pragma unroll
  for (int j = 0; j < 4; ++j)
    #pragma unroll
    for (int i = 0; i < 8; ++i) acc[j][i] = 0.f;

  #pragma unroll 4
  for (int c = 0; c < 64; ++c) {
    float4 b0 = *(const float4*)&wt[c][tdd * 4];
    float4 b1 = *(const float4*)&wt[c][64 + tdd * 4];
    float a0 = fw[kk0 + 0][c];
    float a1 = fw[kk0 + 1][c];
    float a2 = fw[kk0 + 2][c];
    float a3 = fw[kk0 + 3][c];
    acc[0][0] += a0 * b0.x; acc[0][1] += a0 * b0.y; acc[0][2] += a0 * b0.z; acc[0][3] += a0 * b0.w;
    acc[0][4] += a0 * b1.x; acc[0][5] += a0 * b1.y; acc[0][6] += a0 * b1.z; acc[0][7] += a0 * b1.w;
    acc[1][0] += a1 * b0.x; acc[1][1] += a1 * b0.y; acc[1][2] += a1 * b0.z; acc[1][3] += a1 * b0.w;
    acc[1][4] += a1 * b1.x; acc[1][5] += a1 * b1.y; acc[1][6] += a1 * b1.z; acc[1][7] += a1 * b1.w;
    acc[2][0] += a2 * b0.x; acc[2][1] += a2 * b0.y; acc[2][2] += a2 * b0.z; acc[2][3] += a2 * b0.w;
    acc[2][4] += a2 * b1.x; acc[2][5] += a2 * b1.y; acc[2][6] += a2 * b1.z; acc[2][7] += a2 * b1.w;
    acc[3][0] += a3 * b0.x; acc[3][1] += a3 * b0.y; acc[3][2] += a3 * b0.z; acc[3][3] += a3 * b0.w;
    acc[3][4] += a3 * b1.x; acc[3][5] += a3 * b1.y; acc[3][6] += a3 * b1.z; acc[3][7] += a3 * b1.w;
  }

  #pragma unroll
  for (int j = 0; j < 4; ++j) {
    int m = ml[kk0 + j];
    float* orow = out + ((size_t)b * TM_ + T_ + m) * C_ + d0;
    atomicAdd(&orow[tdd * 4 + 0], acc[j][0]);
    atomicAdd(&orow[tdd * 4 + 1], acc[j][1]);
    atomicAdd(&orow[tdd * 4 + 2], acc[j][2]);
    atomicAdd(&orow[tdd * 4 + 3], acc[j][3]);
    atomicAdd(&orow[64 + tdd * 4 + 0], acc[j][4]);
    atomicAdd(&orow[64 + tdd * 4 + 1], acc[j][5]);
    atomicAdd(&orow[64 + tdd * 4 + 2], acc[j][6]);
    atomicAdd(&orow[64 + tdd * 4 + 3], acc[j][7]);
  }
}

// ---------- launch ----------
extern "C" void kernel_launch(void* const* d_in, const int* in_sizes, int n_in,
                              void* d_out, int out_size, void* d_ws, size_t ws_size,
                              hipStream_t stream) {
  (void)in_sizes; (void)n_in; (void)ws_size;
  const float* x = (const float*)d_in[0];
  const float* Wq = (const float*)d_in[1];
  const float* bq = (const float*)d_in[2];
  const float* Wkv = (const float*)d_in[3];
  const float* bkv = (const float*)d_in[4];
  const float* Wexp = (const float*)d_in[5];
  float* out = (float*)d_out;

  // workspace layout (~4.9 MiB total)
  char* ws = (char*)d_ws;
  float* qbuf = (float*)ws;                         // 36,864 B
  float* atbuf = (float*)(ws + 36864);              // 36,864 B
  int* ibuf = (int*)(ws + 73728);                   // 147,456 B
  float* wbuf = (float*)(ws + 221184);              // 147,456 B
  float* sprj = (float*)(ws + 368640);              // 442,368 B
  float* qbb = (float*)(ws + 811008);               // 576 B (pad to 1024)
  float* scg = (float*)(ws + 812032);               // 144*4096*4 = 2,359,296 B
  float* wfp = (float*)(ws + 812032 + 2359296);     // 144*4*768*4 = 1,769,472 B

  int n4 = out_size / 4;
  zero_out_kernel<<<(n4 + 255) / 256, 256, 0, stream>>>((float4*)out, n4);
  q_kernel<<<dim3(T_, 12), 256, 0, stream>>>(x, Wq, bq, qbuf);
  sprj_kernel<<<NBLK_, 256, 0, stream>>>(qbuf, Wkv, bkv, sprj, qbb);
  score_kernel<<<dim3(B_, M_ / 64), 128, 0, stream>>>(x, sprj, qbb, scg);
  topk_kernel<<<NBLK_, 256, 0, stream>>>(scg, ibuf, wbuf);
  wfeat_kernel<<<dim3(NBLK_, 4, 3), 256, 0, stream>>>(x, ibuf, wbuf, wfp);
  attn_token_kernel<<<NBLK_, 256, 0, stream>>>(wfp, Wkv, bkv, atbuf);
  token_out<<<dim3(T_, 12), 256, 0, stream>>>(atbuf, Wexp, out);
  feature_scatter<<<dim3(NBLK_ * 4, 6), 256, 0, stream>>>(x, Wexp, ibuf, wbuf, out);
}

// Round 6
// 433.728 us; speedup vs baseline: 1.2007x; 1.2007x over previous
//
#include <hip/hip_runtime.h>
#include <hip/hip_bf16.h>

#define B_ 4
#define T_ 3
#define M_ 4096
#define C_ 768
#define H_ 12
#define K_ 256
#define HD_ 64
#define TM_ 4099      // T_ + M_
#define SCALE_ 0.125f // HD^-0.5
#define NBLK_ 144     // B*H*T, blk = b*36 + h*3 + t, j = h*3+t

// order-preserving float->uint key (larger float -> larger key)
__device__ __forceinline__ unsigned keyf(float f) {
  unsigned u = __float_as_uint(f);
  return (u & 0x80000000u) ? ~u : (u | 0x80000000u);
}

__device__ __forceinline__ int block_excl_scan256(int v, int tid, int* sbuf) {
  sbuf[tid] = v;
  __syncthreads();
  #pragma unroll
  for (int off = 1; off < 256; off <<= 1) {
    int add = (tid >= off) ? sbuf[tid - off] : 0;
    __syncthreads();
    sbuf[tid] += add;
    __syncthreads();
  }
  int inc = sbuf[tid];
  __syncthreads();
  return inc - v;
}

// ---------- kernels ----------
__global__ void zero_out_kernel(float4* __restrict__ out, int n4) {
  int i = blockIdx.x * 256 + threadIdx.x;
  if (i < n4) out[i] = make_float4(0.f, 0.f, 0.f, 0.f);
}

// q[b,t,d] = sum_c x[b,t,c] * Wq[t,d,c] + bq[t,d]
// grid = (T, 12 dchunks of 64), block = 256. Reads Wq once (4 b per block).
__global__ __launch_bounds__(256) void q_kernel(const float* __restrict__ x,
                                                const float* __restrict__ Wq,
                                                const float* __restrict__ bq,
                                                float* __restrict__ qbuf) {
  int t = blockIdx.x;
  int d0 = blockIdx.y * 64;
  int tid = threadIdx.x;
  __shared__ float ar[B_][C_];
  for (int i = tid; i < B_ * C_; i += 256) {
    int bb = i / C_, c = i % C_;
    ar[bb][c] = x[((size_t)(bb * TM_ + t)) * C_ + c];
  }
  __syncthreads();
  int grp = tid >> 4, ln = tid & 15;
  #pragma unroll
  for (int j = 0; j < 4; ++j) {
    int d = d0 + grp * 4 + j;
    const float4* wr = (const float4*)(Wq + ((size_t)t * C_ + d) * C_);
    float a0 = 0.f, a1 = 0.f, a2 = 0.f, a3 = 0.f;
    #pragma unroll
    for (int it = 0; it < 12; ++it) {
      float4 w4 = wr[ln + 16 * it];
      const float4 x0 = *(const float4*)&ar[0][(ln + 16 * it) * 4];
      const float4 x1 = *(const float4*)&ar[1][(ln + 16 * it) * 4];
      const float4 x2 = *(const float4*)&ar[2][(ln + 16 * it) * 4];
      const float4 x3 = *(const float4*)&ar[3][(ln + 16 * it) * 4];
      a0 += w4.x * x0.x + w4.y * x0.y + w4.z * x0.z + w4.w * x0.w;
      a1 += w4.x * x1.x + w4.y * x1.y + w4.z * x1.z + w4.w * x1.w;
      a2 += w4.x * x2.x + w4.y * x2.y + w4.z * x2.z + w4.w * x2.w;
      a3 += w4.x * x3.x + w4.y * x3.y + w4.z * x3.z + w4.w * x3.w;
    }
    #pragma unroll
    for (int off = 1; off < 16; off <<= 1) {
      a0 += __shfl_xor(a0, off, 16);
      a1 += __shfl_xor(a1, off, 16);
      a2 += __shfl_xor(a2, off, 16);
      a3 += __shfl_xor(a3, off, 16);
    }
    if (ln == 0) {
      float bqv = bq[t * C_ + d];
      qbuf[(size_t)(0 * T_ + t) * C_ + d] = a0 + bqv;
      qbuf[(size_t)(1 * T_ + t) * C_ + d] = a1 + bqv;
      qbuf[(size_t)(2 * T_ + t) * C_ + d] = a2 + bqv;
      qbuf[(size_t)(3 * T_ + t) * C_ + d] = a3 + bqv;
    }
  }
}

// sprjT[(b*768+c)*36 + j] = sum_{i<64} q[b,t,h*64+i] * Wkv[h*64+i, c]
// qbb[blk] = sum_{i<64} q[b,t,h*64+i] * bkv[h*64+i]
__global__ __launch_bounds__(256) void sprj_kernel(const float* __restrict__ qbuf,
                                                   const float* __restrict__ Wkv,
                                                   const float* __restrict__ bkv,
                                                   float* __restrict__ sprjT,
                                                   float* __restrict__ qbb) {
  int blk = blockIdx.x;
  int j = blk % 36;
  int b = blk / 36;
  int t = j % T_;
  int h = j / T_;
  int tid = threadIdx.x;
  __shared__ float qs[HD_];
  if (tid < HD_) qs[tid] = qbuf[((size_t)(b * T_ + t)) * C_ + h * HD_ + tid];
  __syncthreads();
  if (tid == 0) {
    float s = 0.f;
    for (int i = 0; i < HD_; ++i) s += qs[i] * bkv[h * HD_ + i];
    qbb[blk] = s;
  }
  float a0 = 0.f, a1 = 0.f, a2 = 0.f;
  for (int i = 0; i < HD_; ++i) {
    const float* wr = Wkv + ((size_t)(h * HD_ + i)) * C_;
    float qi = qs[i];
    a0 += qi * wr[tid];
    a1 += qi * wr[tid + 256];
    a2 += qi * wr[tid + 512];
  }
  sprjT[((size_t)b * C_ + tid) * 36 + j] = a0;
  sprjT[((size_t)b * C_ + tid + 256) * 36 + j] = a1;
  sprjT[((size_t)b * C_ + tid + 512) * 36 + j] = a2;
}

// score partials: scp[(cc*144 + b*36 + j)*M + m] = partial dot over 192 c's.
// grid = (B, 16 m-tiles of 256, 4 c-chunks), block = 256 (thread = one m).
// sprjT rows are wave-uniform -> s_load; feat staged transposed in LDS.
__global__ __launch_bounds__(256) void score_kernel(const float* __restrict__ x,
                                                    const float* __restrict__ sprjT,
                                                    float* __restrict__ scp) {
  int b = blockIdx.x;
  int m0 = blockIdx.y * 256;
  int cc = blockIdx.z;
  int tid = threadIdx.x;

  __shared__ float fl[32][256]; // [c][m]

  float acc[36];
  #pragma unroll
  for (int j = 0; j < 36; ++j) acc[j] = 0.f;

  const float* fr0 = x + ((size_t)(b * TM_ + T_ + m0 + tid)) * C_ + cc * 192;

  for (int kc = 0; kc < 6; ++kc) {
    float4 v[8];
    const float4* fr = (const float4*)(fr0 + kc * 32);
    #pragma unroll
    for (int i = 0; i < 8; ++i) v[i] = fr[i];
    __syncthreads();
    #pragma unroll
    for (int i = 0; i < 8; ++i) {
      fl[i * 4 + 0][tid] = v[i].x;
      fl[i * 4 + 1][tid] = v[i].y;
      fl[i * 4 + 2][tid] = v[i].z;
      fl[i * 4 + 3][tid] = v[i].w;
    }
    __syncthreads();
    const float* sp = sprjT + ((size_t)b * C_ + cc * 192 + kc * 32) * 36;
    #pragma unroll 4
    for (int k = 0; k < 32; ++k) {
      float f = fl[k][tid];
      const float* sr = sp + k * 36; // uniform -> s_load
      #pragma unroll
      for (int j = 0; j < 36; ++j) acc[j] += f * sr[j];
    }
  }
  float* op = scp + ((size_t)cc * NBLK_ + (size_t)b * 36) * M_ + m0 + tid;
  #pragma unroll
  for (int j = 0; j < 36; ++j) op[(size_t)j * M_] = acc[j];
}

// scg[blk][m] = (sum_cc scp + qbb[blk]) * SCALE. grid = (144, 4), block 256.
__global__ __launch_bounds__(256) void score_reduce(const float* __restrict__ scp,
                                                    const float* __restrict__ qbb,
                                                    float* __restrict__ scg) {
  int blk = blockIdx.x;
  int m = blockIdx.y * 1024 + threadIdx.x * 4;
  float qb = qbb[blk];
  float4 a0 = *(const float4*)&scp[((size_t)0 * NBLK_ + blk) * M_ + m];
  float4 a1 = *(const float4*)&scp[((size_t)1 * NBLK_ + blk) * M_ + m];
  float4 a2 = *(const float4*)&scp[((size_t)2 * NBLK_ + blk) * M_ + m];
  float4 a3 = *(const float4*)&scp[((size_t)3 * NBLK_ + blk) * M_ + m];
  float4 o;
  o.x = (a0.x + a1.x + a2.x + a3.x + qb) * SCALE_;
  o.y = (a0.y + a1.y + a2.y + a3.y + qb) * SCALE_;
  o.z = (a0.z + a1.z + a2.z + a3.z + qb) * SCALE_;
  o.w = (a0.w + a1.w + a2.w + a3.w + qb) * SCALE_;
  *(float4*)&scg[(size_t)blk * M_ + m] = o;
}

// Per blk: exact top-K via radix select (index-ordered ties, = lax.top_k),
// softmax over selected; writes ibuf/wbuf. grid = 144, block = 256.
__global__ __launch_bounds__(256) void topk_kernel(const float* __restrict__ scg,
                                                   int* __restrict__ ibuf,
                                                   float* __restrict__ wbuf) {
  int blk = blockIdx.x;
  int tid = threadIdx.x;

  __shared__ float sc[M_];
  __shared__ unsigned hist[256];
  __shared__ int sbuf[256];
  __shared__ int selm[K_];
  __shared__ float red[256];
  __shared__ int sh_bin, sh_rem;

  const float4* srow = (const float4*)(scg + (size_t)blk * M_);
  for (int i = tid; i < M_ / 4; i += 256) ((float4*)sc)[i] = srow[i];
  __syncthreads();

  // ---- radix select: find K-th largest key ----
  unsigned prefix = 0;
  int remaining = K_;
  for (int shift = 24; shift >= 0; shift -= 8) {
    hist[tid] = 0;
    __syncthreads();
    unsigned pmask = (shift == 24) ? 0u : (0xFFFFFFFFu << (shift + 8));
    #pragma unroll 4
    for (int i = 0; i < 16; ++i) {
      unsigned k = keyf(sc[tid * 16 + i]);
      if ((k & pmask) == prefix) atomicAdd(&hist[(k >> shift) & 255u], 1u);
    }
    __syncthreads();
    int bin = 255 - tid;
    int v = (int)hist[bin];
    int cex = block_excl_scan256(v, tid, sbuf);
    if (cex < remaining && cex + v >= remaining) {
      sh_bin = bin;
      sh_rem = remaining - cex;
    }
    __syncthreads();
    prefix |= ((unsigned)sh_bin) << shift;
    remaining = sh_rem;
    __syncthreads();
  }
  const unsigned tau = prefix;
  const int r = remaining;      // # of ==tau entries to keep (lowest indices)
  const int cgt = K_ - r;       // # of >tau entries

  // ---- compact selection in ascending-index order (deterministic) ----
  int base = tid * 16;
  int myCnt = 0, myTie = 0;
  #pragma unroll
  for (int i = 0; i < 16; i++) {
    unsigned k = keyf(sc[base + i]);
    myCnt += (k > tau);
    myTie += (k == tau);
  }
  int offs = block_excl_scan256(myCnt, tid, sbuf);
  int toffs = block_excl_scan256(myTie, tid, sbuf);
  for (int i = 0; i < 16; i++) {
    int m = base + i;
    unsigned k = keyf(sc[m]);
    if (k > tau) {
      selm[offs++] = m;
    } else if (k == tau) {
      if (toffs < r) selm[cgt + toffs] = m;
      toffs++;
    }
  }
  __syncthreads();

  // ---- softmax over the K selected ----
  int m = selm[tid];
  float val = sc[m];
  red[tid] = val;
  __syncthreads();
  for (int off = 128; off > 0; off >>= 1) {
    if (tid < off) red[tid] = fmaxf(red[tid], red[tid + off]);
    __syncthreads();
  }
  float mx = red[0];
  __syncthreads();
  float e = expf(val - mx);
  red[tid] = e;
  __syncthreads();
  for (int off = 128; off > 0; off >>= 1) {
    if (tid < off) red[tid] += red[tid + off];
    __syncthreads();
  }
  ibuf[(size_t)blk * K_ + tid] = m;
  wbuf[(size_t)blk * K_ + tid] = e / red[0];
}

// wfp[blk*4+kc][c] = sum_{k in chunk} w_k * feat[m_k, c]
// grid = (144, 4, 3 c-segments), block = 256
__global__ __launch_bounds__(256) void wfeat_kernel(const float* __restrict__ x,
                                                    const int* __restrict__ ibuf,
                                                    const float* __restrict__ wbuf,
                                                    float* __restrict__ wfp) {
  int blk = blockIdx.x, kc = blockIdx.y, cseg = blockIdx.z;
  int b = blk / 36;
  int tid = threadIdx.x;
  __shared__ int ml[64];
  __shared__ float wl[64];
  if (tid < 64) {
    ml[tid] = ibuf[(size_t)blk * K_ + kc * 64 + tid];
    wl[tid] = wbuf[(size_t)blk * K_ + kc * 64 + tid];
  }
  __syncthreads();
  int c = cseg * 256 + tid;
  const float* fbase = x + ((size_t)b * TM_ + T_) * C_ + c;
  float a = 0.f;
  #pragma unroll 4
  for (int kk = 0; kk < 64; ++kk) {
    a += wl[kk] * fbase[(size_t)ml[kk] * C_];
  }
  wfp[((size_t)blk * 4 + kc) * C_ + c] = a;
}

// attn_token[b,t,h*64+rr] = (sum_kc wfp) . Wv[row] + bv[row]; grid = 144
__global__ __launch_bounds__(256) void attn_token_kernel(
    const float* __restrict__ wfp, const float* __restrict__ Wkv,
    const float* __restrict__ bkv, float* __restrict__ atbuf) {
  int blk = blockIdx.x;
  int t = blk % T_;
  int h = (blk / T_) % H_;
  int b = blk / (T_ * H_);
  int tid = threadIdx.x;
  __shared__ float wfeat[C_];
  const float* p0 = wfp + ((size_t)blk * 4) * C_;
  #pragma unroll
  for (int j = 0; j < 3; ++j) {
    int c = tid + j * 256;
    wfeat[c] = p0[c] + p0[C_ + c] + p0[2 * C_ + c] + p0[3 * C_ + c];
  }
  __syncthreads();
  int grp = tid >> 4, ln = tid & 15;
  for (int rr = grp; rr < HD_; rr += 16) {
    const float4* wr = (const float4*)(Wkv + ((size_t)(C_ + h * HD_ + rr)) * C_);
    float acc = 0.f;
    #pragma unroll
    for (int it = 0; it < 12; ++it) {
      float4 wv = wr[ln + it * 16];
      const float4 fv = *(const float4*)&wfeat[(ln + it * 16) * 4];
      acc += wv.x * fv.x + wv.y * fv.y + wv.z * fv.z + wv.w * fv.w;
    }
    acc += __shfl_xor(acc, 1, 16);
    acc += __shfl_xor(acc, 2, 16);
    acc += __shfl_xor(acc, 4, 16);
    acc += __shfl_xor(acc, 8, 16);
    if (ln == 0)
      atbuf[((size_t)(b * T_ + t)) * C_ + h * HD_ + rr] =
          acc + bkv[C_ + h * HD_ + rr];
  }
}

// token_output[b,t,d] = sum_c attn_token[b,t,c] * Wexp[t,d,c]
// grid = (T, 12 dchunks of 64), block 256. Reads Wexp once (4 b per block).
__global__ __launch_bounds__(256) void token_out(const float* __restrict__ atbuf,
                                                 const float* __restrict__ Wexp,
                                                 float* __restrict__ out) {
  int t = blockIdx.x;
  int d0 = blockIdx.y * 64;
  int tid = threadIdx.x;
  __shared__ float ar[B_][C_];
  for (int i = tid; i < B_ * C_; i += 256) {
    int bb = i / C_, c = i % C_;
    ar[bb][c] = atbuf[((size_t)(bb * T_ + t)) * C_ + c];
  }
  __syncthreads();
  int grp = tid >> 4, ln = tid & 15;
  #pragma unroll
  for (int j = 0; j < 4; ++j) {
    int d = d0 + grp * 4 + j;
    const float4* wr = (const float4*)(Wexp + ((size_t)t * C_ + d) * C_);
    float a0 = 0.f, a1 = 0.f, a2 = 0.f, a3 = 0.f;
    #pragma unroll
    for (int it = 0; it < 12; ++it) {
      float4 w4 = wr[ln + 16 * it];
      const float4 x0 = *(const float4*)&ar[0][(ln + 16 * it) * 4];
      const float4 x1 = *(const float4*)&ar[1][(ln + 16 * it) * 4];
      const float4 x2 = *(const float4*)&ar[2][(ln + 16 * it) * 4];
      const float4 x3 = *(const float4*)&ar[3][(ln + 16 * it) * 4];
      a0 += w4.x * x0.x + w4.y * x0.y + w4.z * x0.z + w4.w * x0.w;
      a1 += w4.x * x1.x + w4.y * x1.y + w4.z * x1.z + w4.w * x1.w;
      a2 += w4.x * x2.x + w4.y * x2.y + w4.z * x2.z + w4.w * x2.w;
      a3 += w4.x * x3.x + w4.y * x3.y + w4.z * x3.z + w4.w * x3.w;
    }
    #pragma unroll
    for (int off = 1; off < 16; off <<= 1) {
      a0 += __shfl_xor(a0, off, 16);
      a1 += __shfl_xor(a1, off, 16);
      a2 += __shfl_xor(a2, off, 16);
      a3 += __shfl_xor(a3, off, 16);
    }
    if (ln == 0) {
      out[((size_t)0 * TM_ + t) * C_ + d] = a0;
      out[((size_t)1 * TM_ + t) * C_ + d] = a1;
      out[((size_t)2 * TM_ + t) * C_ + d] = a2;
      out[((size_t)3 * TM_ + t) * C_ + d] = a3;
    }
  }
}

// fwg[(bht*256+sel)*64 + c] = w_sel * feat[b, m_sel, h*64+c]
// grid = (144, 4), block = 256 (thread: kk = tid>>2, 16 c's).
__global__ __launch_bounds__(256) void fwg_kernel(const float* __restrict__ x,
                                                  const int* __restrict__ ibuf,
                                                  const float* __restrict__ wbuf,
                                                  float* __restrict__ fwg) {
  int bht = blockIdx.x, ks = blockIdx.y;
  int b = bht / 36;
  int j = bht % 36;
  int h = j / T_;
  int tid = threadIdx.x;
  int kk = tid >> 2, cp = (tid & 3) * 16;
  int sel = ks * 64 + kk;
  int m = ibuf[(size_t)bht * K_ + sel];
  float w = wbuf[(size_t)bht * K_ + sel];
  const float* fr = x + ((size_t)(b * TM_) + T_ + m) * C_ + h * HD_ + cp;
  float* op = fwg + ((size_t)bht * K_ + sel) * 64 + cp;
  #pragma unroll
  for (int i = 0; i < 16; i += 4) {
    float4 f = *(const float4*)(fr + i);
    *(float4*)(op + i) = make_float4(f.x * w, f.y * w, f.z * w, f.w * w);
  }
}

// Sparse feature expansion, SGPR-fw version:
// out[b, T+m_kk, d] += sum_c fwg[kk][c] * Wexp[t,d,h*64+c]
// grid = (576, 3 dchunks), block = 256 (thread = one d). Wexp row segment in
// VGPRs; fw rows are wave-uniform -> scalar loads; R4's coalesced atomic
// burst pattern (64 consecutive d per wave per kk).
__global__ __launch_bounds__(256) void feature_scatter(
    const float* __restrict__ fwg, const float* __restrict__ Wexp,
    const int* __restrict__ ibuf, float* __restrict__ out) {
  int bht = blockIdx.x >> 2, ks = blockIdx.x & 3;
  int b = bht / 36;
  int j = bht % 36;
  int t = j % T_;
  int h = j / T_;
  int tid = threadIdx.x;
  int d = blockIdx.y * 256 + tid;

  __shared__ int ml[64];
  if (tid < 64) ml[tid] = ibuf[(size_t)bht * K_ + ks * 64 + tid];

  float Wr[64];
  const float4* wrow = (const float4*)(Wexp + ((size_t)t * C_ + d) * C_ + h * HD_);
  #pragma unroll
  for (int i = 0; i < 16; ++i) {
    float4 w4 = wrow[i];
    Wr[i * 4 + 0] = w4.x;
    Wr[i * 4 + 1] = w4.y;
    Wr[i * 4 + 2] = w4.z;
    Wr[i * 4 + 3] = w4.w;
  }
  __syncthreads();

  const float* fwb = fwg + ((size_t)bht * K_ + ks * 64) * 64; // uniform
  float* ob = out + ((size_t)b * TM_ + T_) * C_ + d;
  for (int kk = 0; kk < 64; ++kk) {
    const float* fr = fwb + kk * 64; // uniform -> s_load
    float y = 0.f;
    #pragma unroll
    for (int c = 0; c < 64; ++c) y += fr[c] * Wr[c];
    atomicAdd(ob + (size_t)ml[kk] * C_, y);
  }
}

// ---------- launch ----------
extern "C" void kernel_launch(void* const* d_in, const int* in_sizes, int n_in,
                              void* d_out, int out_size, void* d_ws, size_t ws_size,
                              hipStream_t stream) {
  (void)in_sizes; (void)n_in; (void)ws_size;
  const float* x = (const float*)d_in[0];
  const float* Wq = (const float*)d_in[1];
  const float* bq = (const float*)d_in[2];
  const float* Wkv = (const float*)d_in[3];
  const float* bkv = (const float*)d_in[4];
  const float* Wexp = (const float*)d_in[5];
  float* out = (float*)d_out;

  // workspace layout (~23.8 MiB total)
  char* ws = (char*)d_ws;
  float* qbuf = (float*)ws;                          //        36,864 B
  float* atbuf = (float*)(ws + 36864);               //        36,864 B
  int* ibuf = (int*)(ws + 73728);                    //       147,456 B
  float* wbuf = (float*)(ws + 221184);               //       147,456 B
  float* sprjT = (float*)(ws + 368640);              //       442,368 B
  float* qbb = (float*)(ws + 811008);                //     1,024 B pad
  float* scg = (float*)(ws + 812032);                //     2,359,296 B
  float* scp = (float*)(ws + 3171328);               //     9,437,184 B
  float* wfp = (float*)(ws + 12608512);              //     1,769,472 B
  float* fwg = (float*)(ws + 14377984);              //     9,437,184 B

  int n4 = out_size / 4;
  zero_out_kernel<<<(n4 + 255) / 256, 256, 0, stream>>>((float4*)out, n4);
  q_kernel<<<dim3(T_, 12), 256, 0, stream>>>(x, Wq, bq, qbuf);
  sprj_kernel<<<NBLK_, 256, 0, stream>>>(qbuf, Wkv, bkv, sprjT, qbb);
  score_kernel<<<dim3(B_, 16, 4), 256, 0, stream>>>(x, sprjT, scp);
  score_reduce<<<dim3(NBLK_, 4), 256, 0, stream>>>(scp, qbb, scg);
  topk_kernel<<<NBLK_, 256, 0, stream>>>(scg, ibuf, wbuf);
  wfeat_kernel<<<dim3(NBLK_, 4, 3), 256, 0, stream>>>(x, ibuf, wbuf, wfp);
  attn_token_kernel<<<NBLK_, 256, 0, stream>>>(wfp, Wkv, bkv, atbuf);
  token_out<<<dim3(T_, 12), 256, 0, stream>>>(atbuf, Wexp, out);
  fwg_kernel<<<dim3(NBLK_, 4), 256, 0, stream>>>(x, ibuf, wbuf, fwg);
  feature_scatter<<<dim3(NBLK_ * 4, 3), 256, 0, stream>>>(fwg, Wexp, ibuf, out);
}

// Round 7
// 225.690 us; speedup vs baseline: 2.3074x; 1.9218x over previous
//
#include <hip/hip_runtime.h>
#include <hip/hip_bf16.h>

#define B_ 4
#define T_ 3
#define M_ 4096
#define C_ 768
#define H_ 12
#define K_ 256
#define HD_ 64
#define TM_ 4099      // T_ + M_
#define SCALE_ 0.125f // HD^-0.5
#define NBLK_ 144     // B*H*T, blk = b*36 + h*3 + t, j = h*3+t

typedef __attribute__((ext_vector_type(8))) short bf16x8;
typedef __attribute__((ext_vector_type(4))) float f32x4;

// order-preserving float->uint key (larger float -> larger key)
__device__ __forceinline__ unsigned keyf(float f) {
  unsigned u = __float_as_uint(f);
  return (u & 0x80000000u) ? ~u : (u | 0x80000000u);
}

__device__ __forceinline__ unsigned short f2bf(float f) { // RNE
  unsigned u = __float_as_uint(f);
  unsigned r = (u + 0x7FFFu + ((u >> 16) & 1u)) >> 16;
  return (unsigned short)r;
}
__device__ __forceinline__ unsigned pk2(float a, float b) {
  return (unsigned)f2bf(a) | ((unsigned)f2bf(b) << 16);
}

__device__ __forceinline__ int block_excl_scan256(int v, int tid, int* sbuf) {
  sbuf[tid] = v;
  __syncthreads();
  #pragma unroll
  for (int off = 1; off < 256; off <<= 1) {
    int add = (tid >= off) ? sbuf[tid - off] : 0;
    __syncthreads();
    sbuf[tid] += add;
    __syncthreads();
  }
  int inc = sbuf[tid];
  __syncthreads();
  return inc - v;
}

// ---------- kernels ----------
__global__ void zero_out_kernel(float4* __restrict__ out, int n4) {
  int i = blockIdx.x * 256 + threadIdx.x;
  if (i < n4) out[i] = make_float4(0.f, 0.f, 0.f, 0.f);
}

// q[b,t,d] = sum_c x[b,t,c] * Wq[t,d,c] + bq[t,d]
// grid = (T, 12 dchunks of 64), block = 256. Reads Wq once (4 b per block).
__global__ __launch_bounds__(256) void q_kernel(const float* __restrict__ x,
                                                const float* __restrict__ Wq,
                                                const float* __restrict__ bq,
                                                float* __restrict__ qbuf) {
  int t = blockIdx.x;
  int d0 = blockIdx.y * 64;
  int tid = threadIdx.x;
  __shared__ float ar[B_][C_];
  for (int i = tid; i < B_ * C_; i += 256) {
    int bb = i / C_, c = i % C_;
    ar[bb][c] = x[((size_t)(bb * TM_ + t)) * C_ + c];
  }
  __syncthreads();
  int grp = tid >> 4, ln = tid & 15;
  #pragma unroll
  for (int j = 0; j < 4; ++j) {
    int d = d0 + grp * 4 + j;
    const float4* wr = (const float4*)(Wq + ((size_t)t * C_ + d) * C_);
    float a0 = 0.f, a1 = 0.f, a2 = 0.f, a3 = 0.f;
    #pragma unroll
    for (int it = 0; it < 12; ++it) {
      float4 w4 = wr[ln + 16 * it];
      const float4 x0 = *(const float4*)&ar[0][(ln + 16 * it) * 4];
      const float4 x1 = *(const float4*)&ar[1][(ln + 16 * it) * 4];
      const float4 x2 = *(const float4*)&ar[2][(ln + 16 * it) * 4];
      const float4 x3 = *(const float4*)&ar[3][(ln + 16 * it) * 4];
      a0 += w4.x * x0.x + w4.y * x0.y + w4.z * x0.z + w4.w * x0.w;
      a1 += w4.x * x1.x + w4.y * x1.y + w4.z * x1.z + w4.w * x1.w;
      a2 += w4.x * x2.x + w4.y * x2.y + w4.z * x2.z + w4.w * x2.w;
      a3 += w4.x * x3.x + w4.y * x3.y + w4.z * x3.z + w4.w * x3.w;
    }
    #pragma unroll
    for (int off = 1; off < 16; off <<= 1) {
      a0 += __shfl_xor(a0, off, 16);
      a1 += __shfl_xor(a1, off, 16);
      a2 += __shfl_xor(a2, off, 16);
      a3 += __shfl_xor(a3, off, 16);
    }
    if (ln == 0) {
      float bqv = bq[t * C_ + d];
      qbuf[(size_t)(0 * T_ + t) * C_ + d] = a0 + bqv;
      qbuf[(size_t)(1 * T_ + t) * C_ + d] = a1 + bqv;
      qbuf[(size_t)(2 * T_ + t) * C_ + d] = a2 + bqv;
      qbuf[(size_t)(3 * T_ + t) * C_ + d] = a3 + bqv;
    }
  }
}

// sprjT[(b*768+c)*36 + j] = sum_{i<64} q[b,t,h*64+i] * Wkv[h*64+i, c]
// qbb[blk] = sum_{i<64} q[b,t,h*64+i] * bkv[h*64+i]
__global__ __launch_bounds__(256) void sprj_kernel(const float* __restrict__ qbuf,
                                                   const float* __restrict__ Wkv,
                                                   const float* __restrict__ bkv,
                                                   float* __restrict__ sprjT,
                                                   float* __restrict__ qbb) {
  int blk = blockIdx.x;
  int j = blk % 36;
  int b = blk / 36;
  int t = j % T_;
  int h = j / T_;
  int tid = threadIdx.x;
  __shared__ float qs[HD_];
  if (tid < HD_) qs[tid] = qbuf[((size_t)(b * T_ + t)) * C_ + h * HD_ + tid];
  __syncthreads();
  if (tid == 0) {
    float s = 0.f;
    for (int i = 0; i < HD_; ++i) s += qs[i] * bkv[h * HD_ + i];
    qbb[blk] = s;
  }
  float a0 = 0.f, a1 = 0.f, a2 = 0.f;
  for (int i = 0; i < HD_; ++i) {
    const float* wr = Wkv + ((size_t)(h * HD_ + i)) * C_;
    float qi = qs[i];
    a0 += qi * wr[tid];
    a1 += qi * wr[tid + 256];
    a2 += qi * wr[tid + 512];
  }
  sprjT[((size_t)b * C_ + tid) * 36 + j] = a0;
  sprjT[((size_t)b * C_ + tid + 256) * 36 + j] = a1;
  sprjT[((size_t)b * C_ + tid + 512) * 36 + j] = a2;
}

// score partials: scp[(cc*144 + b*36 + j)*M + m] = partial dot over 192 c's.
// grid = (B, 16 m-tiles of 256, 4 c-chunks), block = 256 (thread = one m).
__global__ __launch_bounds__(256) void score_kernel(const float* __restrict__ x,
                                                    const float* __restrict__ sprjT,
                                                    float* __restrict__ scp) {
  int b = blockIdx.x;
  int m0 = blockIdx.y * 256;
  int cc = blockIdx.z;
  int tid = threadIdx.x;

  __shared__ float fl[32][256]; // [c][m]

  float acc[36];
  #pragma unroll
  for (int j = 0; j < 36; ++j) acc[j] = 0.f;

  const float* fr0 = x + ((size_t)(b * TM_ + T_ + m0 + tid)) * C_ + cc * 192;

  for (int kc = 0; kc < 6; ++kc) {
    float4 v[8];
    const float4* fr = (const float4*)(fr0 + kc * 32);
    #pragma unroll
    for (int i = 0; i < 8; ++i) v[i] = fr[i];
    __syncthreads();
    #pragma unroll
    for (int i = 0; i < 8; ++i) {
      fl[i * 4 + 0][tid] = v[i].x;
      fl[i * 4 + 1][tid] = v[i].y;
      fl[i * 4 + 2][tid] = v[i].z;
      fl[i * 4 + 3][tid] = v[i].w;
    }
    __syncthreads();
    const float* sp = sprjT + ((size_t)b * C_ + cc * 192 + kc * 32) * 36;
    #pragma unroll 4
    for (int k = 0; k < 32; ++k) {
      float f = fl[k][tid];
      const float* sr = sp + k * 36; // uniform -> s_load
      #pragma unroll
      for (int j = 0; j < 36; ++j) acc[j] += f * sr[j];
    }
  }
  float* op = scp + ((size_t)cc * NBLK_ + (size_t)b * 36) * M_ + m0 + tid;
  #pragma unroll
  for (int j = 0; j < 36; ++j) op[(size_t)j * M_] = acc[j];
}

// scg[blk][m] = (sum_cc scp + qbb[blk]) * SCALE. grid = (144, 4), block 256.
__global__ __launch_bounds__(256) void score_reduce(const float* __restrict__ scp,
                                                    const float* __restrict__ qbb,
                                                    float* __restrict__ scg) {
  int blk = blockIdx.x;
  int m = blockIdx.y * 1024 + threadIdx.x * 4;
  float qb = qbb[blk];
  float4 a0 = *(const float4*)&scp[((size_t)0 * NBLK_ + blk) * M_ + m];
  float4 a1 = *(const float4*)&scp[((size_t)1 * NBLK_ + blk) * M_ + m];
  float4 a2 = *(const float4*)&scp[((size_t)2 * NBLK_ + blk) * M_ + m];
  float4 a3 = *(const float4*)&scp[((size_t)3 * NBLK_ + blk) * M_ + m];
  float4 o;
  o.x = (a0.x + a1.x + a2.x + a3.x + qb) * SCALE_;
  o.y = (a0.y + a1.y + a2.y + a3.y + qb) * SCALE_;
  o.z = (a0.z + a1.z + a2.z + a3.z + qb) * SCALE_;
  o.w = (a0.w + a1.w + a2.w + a3.w + qb) * SCALE_;
  *(float4*)&scg[(size_t)blk * M_ + m] = o;
}

// Per blk: exact top-K via radix select (index-ordered ties, = lax.top_k),
// softmax over selected; writes ibuf/wbuf. grid = 144, block = 256.
__global__ __launch_bounds__(256) void topk_kernel(const float* __restrict__ scg,
                                                   int* __restrict__ ibuf,
                                                   float* __restrict__ wbuf) {
  int blk = blockIdx.x;
  int tid = threadIdx.x;

  __shared__ float sc[M_];
  __shared__ unsigned hist[256];
  __shared__ int sbuf[256];
  __shared__ int selm[K_];
  __shared__ float red[256];
  __shared__ int sh_bin, sh_rem;

  const float4* srow = (const float4*)(scg + (size_t)blk * M_);
  for (int i = tid; i < M_ / 4; i += 256) ((float4*)sc)[i] = srow[i];
  __syncthreads();

  // ---- radix select: find K-th largest key ----
  unsigned prefix = 0;
  int remaining = K_;
  for (int shift = 24; shift >= 0; shift -= 8) {
    hist[tid] = 0;
    __syncthreads();
    unsigned pmask = (shift == 24) ? 0u : (0xFFFFFFFFu << (shift + 8));
    #pragma unroll 4
    for (int i = 0; i < 16; ++i) {
      unsigned k = keyf(sc[tid * 16 + i]);
      if ((k & pmask) == prefix) atomicAdd(&hist[(k >> shift) & 255u], 1u);
    }
    __syncthreads();
    int bin = 255 - tid;
    int v = (int)hist[bin];
    int cex = block_excl_scan256(v, tid, sbuf);
    if (cex < remaining && cex + v >= remaining) {
      sh_bin = bin;
      sh_rem = remaining - cex;
    }
    __syncthreads();
    prefix |= ((unsigned)sh_bin) << shift;
    remaining = sh_rem;
    __syncthreads();
  }
  const unsigned tau = prefix;
  const int r = remaining;      // # of ==tau entries to keep (lowest indices)
  const int cgt = K_ - r;       // # of >tau entries

  // ---- compact selection in ascending-index order (deterministic) ----
  int base = tid * 16;
  int myCnt = 0, myTie = 0;
  #pragma unroll
  for (int i = 0; i < 16; i++) {
    unsigned k = keyf(sc[base + i]);
    myCnt += (k > tau);
    myTie += (k == tau);
  }
  int offs = block_excl_scan256(myCnt, tid, sbuf);
  int toffs = block_excl_scan256(myTie, tid, sbuf);
  for (int i = 0; i < 16; i++) {
    int m = base + i;
    unsigned k = keyf(sc[m]);
    if (k > tau) {
      selm[offs++] = m;
    } else if (k == tau) {
      if (toffs < r) selm[cgt + toffs] = m;
      toffs++;
    }
  }
  __syncthreads();

  // ---- softmax over the K selected ----
  int m = selm[tid];
  float val = sc[m];
  red[tid] = val;
  __syncthreads();
  for (int off = 128; off > 0; off >>= 1) {
    if (tid < off) red[tid] = fmaxf(red[tid], red[tid + off]);
    __syncthreads();
  }
  float mx = red[0];
  __syncthreads();
  float e = expf(val - mx);
  red[tid] = e;
  __syncthreads();
  for (int off = 128; off > 0; off >>= 1) {
    if (tid < off) red[tid] += red[tid + off];
    __syncthreads();
  }
  ibuf[(size_t)blk * K_ + tid] = m;
  wbuf[(size_t)blk * K_ + tid] = e / red[0];
}

// wfp[blk*4+kc][c] = sum_{k in chunk} w_k * feat[m_k, c]
// grid = (144, 4, 3 c-segments), block = 256
__global__ __launch_bounds__(256) void wfeat_kernel(const float* __restrict__ x,
                                                    const int* __restrict__ ibuf,
                                                    const float* __restrict__ wbuf,
                                                    float* __restrict__ wfp) {
  int blk = blockIdx.x, kc = blockIdx.y, cseg = blockIdx.z;
  int b = blk / 36;
  int tid = threadIdx.x;
  __shared__ int ml[64];
  __shared__ float wl[64];
  if (tid < 64) {
    ml[tid] = ibuf[(size_t)blk * K_ + kc * 64 + tid];
    wl[tid] = wbuf[(size_t)blk * K_ + kc * 64 + tid];
  }
  __syncthreads();
  int c = cseg * 256 + tid;
  const float* fbase = x + ((size_t)b * TM_ + T_) * C_ + c;
  float a = 0.f;
  #pragma unroll 4
  for (int kk = 0; kk < 64; ++kk) {
    a += wl[kk] * fbase[(size_t)ml[kk] * C_];
  }
  wfp[((size_t)blk * 4 + kc) * C_ + c] = a;
}

// attn_token[b,t,h*64+rr] = (sum_kc wfp) . Wv[row] + bv[row]; grid = 144
__global__ __launch_bounds__(256) void attn_token_kernel(
    const float* __restrict__ wfp, const float* __restrict__ Wkv,
    const float* __restrict__ bkv, float* __restrict__ atbuf) {
  int blk = blockIdx.x;
  int t = blk % T_;
  int h = (blk / T_) % H_;
  int b = blk / (T_ * H_);
  int tid = threadIdx.x;
  __shared__ float wfeat[C_];
  const float* p0 = wfp + ((size_t)blk * 4) * C_;
  #pragma unroll
  for (int j = 0; j < 3; ++j) {
    int c = tid + j * 256;
    wfeat[c] = p0[c] + p0[C_ + c] + p0[2 * C_ + c] + p0[3 * C_ + c];
  }
  __syncthreads();
  int grp = tid >> 4, ln = tid & 15;
  for (int rr = grp; rr < HD_; rr += 16) {
    const float4* wr = (const float4*)(Wkv + ((size_t)(C_ + h * HD_ + rr)) * C_);
    float acc = 0.f;
    #pragma unroll
    for (int it = 0; it < 12; ++it) {
      float4 wv = wr[ln + it * 16];
      const float4 fv = *(const float4*)&wfeat[(ln + it * 16) * 4];
      acc += wv.x * fv.x + wv.y * fv.y + wv.z * fv.z + wv.w * fv.w;
    }
    acc += __shfl_xor(acc, 1, 16);
    acc += __shfl_xor(acc, 2, 16);
    acc += __shfl_xor(acc, 4, 16);
    acc += __shfl_xor(acc, 8, 16);
    if (ln == 0)
      atbuf[((size_t)(b * T_ + t)) * C_ + h * HD_ + rr] =
          acc + bkv[C_ + h * HD_ + rr];
  }
}

// token_output[b,t,d] = sum_c attn_token[b,t,c] * Wexp[t,d,c]
// grid = (T, 12 dchunks of 64), block 256. Reads Wexp once (4 b per block).
__global__ __launch_bounds__(256) void token_out(const float* __restrict__ atbuf,
                                                 const float* __restrict__ Wexp,
                                                 float* __restrict__ out) {
  int t = blockIdx.x;
  int d0 = blockIdx.y * 64;
  int tid = threadIdx.x;
  __shared__ float ar[B_][C_];
  for (int i = tid; i < B_ * C_; i += 256) {
    int bb = i / C_, c = i % C_;
    ar[bb][c] = atbuf[((size_t)(bb * T_ + t)) * C_ + c];
  }
  __syncthreads();
  int grp = tid >> 4, ln = tid & 15;
  #pragma unroll
  for (int j = 0; j < 4; ++j) {
    int d = d0 + grp * 4 + j;
    const float4* wr = (const float4*)(Wexp + ((size_t)t * C_ + d) * C_);
    float a0 = 0.f, a1 = 0.f, a2 = 0.f, a3 = 0.f;
    #pragma unroll
    for (int it = 0; it < 12; ++it) {
      float4 w4 = wr[ln + 16 * it];
      const float4 x0 = *(const float4*)&ar[0][(ln + 16 * it) * 4];
      const float4 x1 = *(const float4*)&ar[1][(ln + 16 * it) * 4];
      const float4 x2 = *(const float4*)&ar[2][(ln + 16 * it) * 4];
      const float4 x3 = *(const float4*)&ar[3][(ln + 16 * it) * 4];
      a0 += w4.x * x0.x + w4.y * x0.y + w4.z * x0.z + w4.w * x0.w;
      a1 += w4.x * x1.x + w4.y * x1.y + w4.z * x1.z + w4.w * x1.w;
      a2 += w4.x * x2.x + w4.y * x2.y + w4.z * x2.z + w4.w * x2.w;
      a3 += w4.x * x3.x + w4.y * x3.y + w4.z * x3.z + w4.w * x3.w;
    }
    #pragma unroll
    for (int off = 1; off < 16; off <<= 1) {
      a0 += __shfl_xor(a0, off, 16);
      a1 += __shfl_xor(a1, off, 16);
      a2 += __shfl_xor(a2, off, 16);
      a3 += __shfl_xor(a3, off, 16);
    }
    if (ln == 0) {
      out[((size_t)0 * TM_ + t) * C_ + d] = a0;
      out[((size_t)1 * TM_ + t) * C_ + d] = a1;
      out[((size_t)2 * TM_ + t) * C_ + d] = a2;
      out[((size_t)3 * TM_ + t) * C_ + d] = a3;
    }
  }
}

// Sparse feature expansion via MFMA GEMM per (t,h):
//   Y[64 rows][768 d] = FW[64x64 c] @ WexpT[64 c x 768 d], rows = (ks-chunk of
//   selections), then atomic-add rows into out[b, T+m, :].
// grid = (36 th, 16 rowtiles: b*4+ks), block = 256 (4 waves).
// LDS: fw bf16 [64][72] + wt bf16 [192][72] (+pad: 2-way reads = free).
__global__ __launch_bounds__(256) void scatter_mfma(
    const float* __restrict__ x, const float* __restrict__ Wexp,
    const int* __restrict__ ibuf, const float* __restrict__ wbuf,
    float* __restrict__ out) {
  int th = blockIdx.x;
  int h = th / T_, t = th % T_;
  int rt = blockIdx.y;
  int b = rt >> 2, ks = rt & 3;
  int bht = b * 36 + th;
  int tid = threadIdx.x;

  __shared__ unsigned short fw[64][72];
  __shared__ unsigned short wt[192][72];
  __shared__ int ml[64];

  if (tid < 64) ml[tid] = ibuf[(size_t)bht * K_ + ks * 64 + tid];
  // stage fw (bf16 of w * feat slice): thread = (kk, 16-c chunk)
  {
    int kk = tid >> 2, cp = (tid & 3) * 16;
    int sel = ks * 64 + kk;
    int m = ibuf[(size_t)bht * K_ + sel];
    float w = wbuf[(size_t)bht * K_ + sel];
    const float* fr = x + ((size_t)(b * TM_) + T_ + m) * C_ + h * HD_ + cp;
    float4 f0 = *(const float4*)(fr + 0);
    float4 f1 = *(const float4*)(fr + 4);
    float4 f2 = *(const float4*)(fr + 8);
    float4 f3 = *(const float4*)(fr + 12);
    uint4 u0 = make_uint4(pk2(f0.x * w, f0.y * w), pk2(f0.z * w, f0.w * w),
                          pk2(f1.x * w, f1.y * w), pk2(f1.z * w, f1.w * w));
    uint4 u1 = make_uint4(pk2(f2.x * w, f2.y * w), pk2(f2.z * w, f2.w * w),
                          pk2(f3.x * w, f3.y * w), pk2(f3.z * w, f3.w * w));
    *(uint4*)&fw[kk][cp] = u0;
    *(uint4*)&fw[kk][cp + 8] = u1;
  }
  __syncthreads();

  int lane = tid & 63, wave = tid >> 6;
  int lrow = lane & 15, lk8 = (lane >> 4) * 8, g4 = (lane >> 4) * 4;

  for (int dc = 0; dc < 4; ++dc) {
    // stage wt[dd][c] = bf16(Wexp[t, dc*192+dd, h*64+c]) — coalesced rows
    {
      #pragma unroll
      for (int r2 = 0; r2 < 3; ++r2) {
        int idx = r2 * 256 + tid;
        int dd = idx >> 2, cq = (idx & 3) * 16;
        const float* wr =
            Wexp + ((size_t)t * C_ + dc * 192 + dd) * C_ + h * HD_ + cq;
        float4 f0 = *(const float4*)(wr + 0);
        float4 f1 = *(const float4*)(wr + 4);
        float4 f2 = *(const float4*)(wr + 8);
        float4 f3 = *(const float4*)(wr + 12);
        uint4 u0 = make_uint4(pk2(f0.x, f0.y), pk2(f0.z, f0.w),
                              pk2(f1.x, f1.y), pk2(f1.z, f1.w));
        uint4 u1 = make_uint4(pk2(f2.x, f2.y), pk2(f2.z, f2.w),
                              pk2(f3.x, f3.y), pk2(f3.z, f3.w));
        *(uint4*)&wt[dd][cq] = u0;
        *(uint4*)&wt[dd][cq + 8] = u1;
      }
    }
    __syncthreads();

    f32x4 acc[12];
    #pragma unroll
    for (int n = 0; n < 12; ++n) acc[n] = (f32x4){0.f, 0.f, 0.f, 0.f};

    #pragma unroll
    for (int ks2 = 0; ks2 < 2; ++ks2) {
      bf16x8 a = *(const bf16x8*)&fw[wave * 16 + lrow][ks2 * 32 + lk8];
      #pragma unroll
      for (int n = 0; n < 12; ++n) {
        bf16x8 bfr = *(const bf16x8*)&wt[n * 16 + lrow][ks2 * 32 + lk8];
        acc[n] = __builtin_amdgcn_mfma_f32_16x16x32_bf16(a, bfr, acc[n], 0, 0, 0);
      }
    }

    // epilogue: D col = lane&15 (d), row = (lane>>4)*4 + q (local row)
    #pragma unroll
    for (int n = 0; n < 12; ++n) {
      int d = dc * 192 + n * 16 + lrow;
      #pragma unroll
      for (int q = 0; q < 4; ++q) {
        int row = wave * 16 + g4 + q;
        int mrow = ml[row];
        atomicAdd(&out[((size_t)b * TM_ + T_ + mrow) * C_ + d], acc[n][q]);
      }
    }
    __syncthreads(); // all reads of wt done before next-dc overwrite
  }
}

// ---------- launch ----------
extern "C" void kernel_launch(void* const* d_in, const int* in_sizes, int n_in,
                              void* d_out, int out_size, void* d_ws, size_t ws_size,
                              hipStream_t stream) {
  (void)in_sizes; (void)n_in; (void)ws_size;
  const float* x = (const float*)d_in[0];
  const float* Wq = (const float*)d_in[1];
  const float* bq = (const float*)d_in[2];
  const float* Wkv = (const float*)d_in[3];
  const float* bkv = (const float*)d_in[4];
  const float* Wexp = (const float*)d_in[5];
  float* out = (float*)d_out;

  // workspace layout (~14.4 MiB used)
  char* ws = (char*)d_ws;
  float* qbuf = (float*)ws;                          //        36,864 B
  float* atbuf = (float*)(ws + 36864);               //        36,864 B
  int* ibuf = (int*)(ws + 73728);                    //       147,456 B
  float* wbuf = (float*)(ws + 221184);               //       147,456 B
  float* sprjT = (float*)(ws + 368640);              //       442,368 B
  float* qbb = (float*)(ws + 811008);                //     1,024 B pad
  float* scg = (float*)(ws + 812032);                //     2,359,296 B
  float* scp = (float*)(ws + 3171328);               //     9,437,184 B
  float* wfp = (float*)(ws + 12608512);              //     1,769,472 B

  int n4 = out_size / 4;
  zero_out_kernel<<<(n4 + 255) / 256, 256, 0, stream>>>((float4*)out, n4);
  q_kernel<<<dim3(T_, 12), 256, 0, stream>>>(x, Wq, bq, qbuf);
  sprj_kernel<<<NBLK_, 256, 0, stream>>>(qbuf, Wkv, bkv, sprjT, qbb);
  score_kernel<<<dim3(B_, 16, 4), 256, 0, stream>>>(x, sprjT, scp);
  score_reduce<<<dim3(NBLK_, 4), 256, 0, stream>>>(scp, qbb, scg);
  topk_kernel<<<NBLK_, 256, 0, stream>>>(scg, ibuf, wbuf);
  wfeat_kernel<<<dim3(NBLK_, 4, 3), 256, 0, stream>>>(x, ibuf, wbuf, wfp);
  attn_token_kernel<<<NBLK_, 256, 0, stream>>>(wfp, Wkv, bkv, atbuf);
  token_out<<<dim3(T_, 12), 256, 0, stream>>>(atbuf, Wexp, out);
  scatter_mfma<<<dim3(36, 16), 256, 0, stream>>>(x, Wexp, ibuf, wbuf, out);
}

// Round 8
// 224.478 us; speedup vs baseline: 2.3199x; 1.0054x over previous
//
#include <hip/hip_runtime.h>
#include <hip/hip_bf16.h>

#define B_ 4
#define T_ 3
#define M_ 4096
#define C_ 768
#define H_ 12
#define K_ 256
#define HD_ 64
#define TM_ 4099      // T_ + M_
#define SCALE_ 0.125f // HD^-0.5
#define NBLK_ 144     // B*H*T, blk = b*36 + h*3 + t, j = h*3+t

typedef __attribute__((ext_vector_type(8))) short bf16x8;
typedef __attribute__((ext_vector_type(4))) float f32x4;

// order-preserving float->uint key (larger float -> larger key)
__device__ __forceinline__ unsigned keyf(float f) {
  unsigned u = __float_as_uint(f);
  return (u & 0x80000000u) ? ~u : (u | 0x80000000u);
}

__device__ __forceinline__ unsigned short f2bf(float f) { // RNE
  unsigned u = __float_as_uint(f);
  unsigned r = (u + 0x7FFFu + ((u >> 16) & 1u)) >> 16;
  return (unsigned short)r;
}
__device__ __forceinline__ unsigned pk2(float a, float b) {
  return (unsigned)f2bf(a) | ((unsigned)f2bf(b) << 16);
}

__device__ __forceinline__ int block_excl_scan256(int v, int tid, int* sbuf) {
  sbuf[tid] = v;
  __syncthreads();
  #pragma unroll
  for (int off = 1; off < 256; off <<= 1) {
    int add = (tid >= off) ? sbuf[tid - off] : 0;
    __syncthreads();
    sbuf[tid] += add;
    __syncthreads();
  }
  int inc = sbuf[tid];
  __syncthreads();
  return inc - v;
}

// ---------- kernels ----------
__global__ void zero_out_kernel(float4* __restrict__ out, int n4) {
  int i = blockIdx.x * 256 + threadIdx.x;
  if (i < n4) out[i] = make_float4(0.f, 0.f, 0.f, 0.f);
}

// q[b,t,d] = sum_c x[b,t,c] * Wq[t,d,c] + bq[t,d]
// grid = (T, 12 dchunks of 64), block = 256. Reads Wq once (4 b per block).
__global__ __launch_bounds__(256) void q_kernel(const float* __restrict__ x,
                                                const float* __restrict__ Wq,
                                                const float* __restrict__ bq,
                                                float* __restrict__ qbuf) {
  int t = blockIdx.x;
  int d0 = blockIdx.y * 64;
  int tid = threadIdx.x;
  __shared__ float ar[B_][C_];
  for (int i = tid; i < B_ * C_; i += 256) {
    int bb = i / C_, c = i % C_;
    ar[bb][c] = x[((size_t)(bb * TM_ + t)) * C_ + c];
  }
  __syncthreads();
  int grp = tid >> 4, ln = tid & 15;
  #pragma unroll
  for (int j = 0; j < 4; ++j) {
    int d = d0 + grp * 4 + j;
    const float4* wr = (const float4*)(Wq + ((size_t)t * C_ + d) * C_);
    float a0 = 0.f, a1 = 0.f, a2 = 0.f, a3 = 0.f;
    #pragma unroll
    for (int it = 0; it < 12; ++it) {
      float4 w4 = wr[ln + 16 * it];
      const float4 x0 = *(const float4*)&ar[0][(ln + 16 * it) * 4];
      const float4 x1 = *(const float4*)&ar[1][(ln + 16 * it) * 4];
      const float4 x2 = *(const float4*)&ar[2][(ln + 16 * it) * 4];
      const float4 x3 = *(const float4*)&ar[3][(ln + 16 * it) * 4];
      a0 += w4.x * x0.x + w4.y * x0.y + w4.z * x0.z + w4.w * x0.w;
      a1 += w4.x * x1.x + w4.y * x1.y + w4.z * x1.z + w4.w * x1.w;
      a2 += w4.x * x2.x + w4.y * x2.y + w4.z * x2.z + w4.w * x2.w;
      a3 += w4.x * x3.x + w4.y * x3.y + w4.z * x3.z + w4.w * x3.w;
    }
    #pragma unroll
    for (int off = 1; off < 16; off <<= 1) {
      a0 += __shfl_xor(a0, off, 16);
      a1 += __shfl_xor(a1, off, 16);
      a2 += __shfl_xor(a2, off, 16);
      a3 += __shfl_xor(a3, off, 16);
    }
    if (ln == 0) {
      float bqv = bq[t * C_ + d];
      qbuf[(size_t)(0 * T_ + t) * C_ + d] = a0 + bqv;
      qbuf[(size_t)(1 * T_ + t) * C_ + d] = a1 + bqv;
      qbuf[(size_t)(2 * T_ + t) * C_ + d] = a2 + bqv;
      qbuf[(size_t)(3 * T_ + t) * C_ + d] = a3 + bqv;
    }
  }
}

// sprjT[(b*768+c)*36 + j] = sum_{i<64} q[b,t,h*64+i] * Wkv[h*64+i, c]
// qbb[blk] = sum_{i<64} q[b,t,h*64+i] * bkv[h*64+i]
__global__ __launch_bounds__(256) void sprj_kernel(const float* __restrict__ qbuf,
                                                   const float* __restrict__ Wkv,
                                                   const float* __restrict__ bkv,
                                                   float* __restrict__ sprjT,
                                                   float* __restrict__ qbb) {
  int blk = blockIdx.x;
  int j = blk % 36;
  int b = blk / 36;
  int t = j % T_;
  int h = j / T_;
  int tid = threadIdx.x;
  __shared__ float qs[HD_];
  if (tid < HD_) qs[tid] = qbuf[((size_t)(b * T_ + t)) * C_ + h * HD_ + tid];
  __syncthreads();
  if (tid == 0) {
    float s = 0.f;
    for (int i = 0; i < HD_; ++i) s += qs[i] * bkv[h * HD_ + i];
    qbb[blk] = s;
  }
  float a0 = 0.f, a1 = 0.f, a2 = 0.f;
  for (int i = 0; i < HD_; ++i) {
    const float* wr = Wkv + ((size_t)(h * HD_ + i)) * C_;
    float qi = qs[i];
    a0 += qi * wr[tid];
    a1 += qi * wr[tid + 256];
    a2 += qi * wr[tid + 512];
  }
  sprjT[((size_t)b * C_ + tid) * 36 + j] = a0;
  sprjT[((size_t)b * C_ + tid + 256) * 36 + j] = a1;
  sprjT[((size_t)b * C_ + tid + 512) * 36 + j] = a2;
}

// score partials: scp[(cc*144 + b*36 + j)*M + m] = partial dot over 192 c's.
// grid = (B, 16 m-tiles of 256, 4 c-chunks), block = 256 (thread = one m).
__global__ __launch_bounds__(256) void score_kernel(const float* __restrict__ x,
                                                    const float* __restrict__ sprjT,
                                                    float* __restrict__ scp) {
  int b = blockIdx.x;
  int m0 = blockIdx.y * 256;
  int cc = blockIdx.z;
  int tid = threadIdx.x;

  __shared__ float fl[32][256]; // [c][m]

  float acc[36];
  #pragma unroll
  for (int j = 0; j < 36; ++j) acc[j] = 0.f;

  const float* fr0 = x + ((size_t)(b * TM_ + T_ + m0 + tid)) * C_ + cc * 192;

  for (int kc = 0; kc < 6; ++kc) {
    float4 v[8];
    const float4* fr = (const float4*)(fr0 + kc * 32);
    #pragma unroll
    for (int i = 0; i < 8; ++i) v[i] = fr[i];
    __syncthreads();
    #pragma unroll
    for (int i = 0; i < 8; ++i) {
      fl[i * 4 + 0][tid] = v[i].x;
      fl[i * 4 + 1][tid] = v[i].y;
      fl[i * 4 + 2][tid] = v[i].z;
      fl[i * 4 + 3][tid] = v[i].w;
    }
    __syncthreads();
    const float* sp = sprjT + ((size_t)b * C_ + cc * 192 + kc * 32) * 36;
    #pragma unroll 4
    for (int k = 0; k < 32; ++k) {
      float f = fl[k][tid];
      const float* sr = sp + k * 36; // uniform -> s_load
      #pragma unroll
      for (int j = 0; j < 36; ++j) acc[j] += f * sr[j];
    }
  }
  float* op = scp + ((size_t)cc * NBLK_ + (size_t)b * 36) * M_ + m0 + tid;
  #pragma unroll
  for (int j = 0; j < 36; ++j) op[(size_t)j * M_] = acc[j];
}

// scg[blk][m] = (sum_cc scp + qbb[blk]) * SCALE. grid = (144, 4), block 256.
__global__ __launch_bounds__(256) void score_reduce(const float* __restrict__ scp,
                                                    const float* __restrict__ qbb,
                                                    float* __restrict__ scg) {
  int blk = blockIdx.x;
  int m = blockIdx.y * 1024 + threadIdx.x * 4;
  float qb = qbb[blk];
  float4 a0 = *(const float4*)&scp[((size_t)0 * NBLK_ + blk) * M_ + m];
  float4 a1 = *(const float4*)&scp[((size_t)1 * NBLK_ + blk) * M_ + m];
  float4 a2 = *(const float4*)&scp[((size_t)2 * NBLK_ + blk) * M_ + m];
  float4 a3 = *(const float4*)&scp[((size_t)3 * NBLK_ + blk) * M_ + m];
  float4 o;
  o.x = (a0.x + a1.x + a2.x + a3.x + qb) * SCALE_;
  o.y = (a0.y + a1.y + a2.y + a3.y + qb) * SCALE_;
  o.z = (a0.z + a1.z + a2.z + a3.z + qb) * SCALE_;
  o.w = (a0.w + a1.w + a2.w + a3.w + qb) * SCALE_;
  *(float4*)&scg[(size_t)blk * M_ + m] = o;
}

// Per blk: exact top-K via radix select (index-ordered ties, = lax.top_k),
// softmax over selected; writes ibuf/wbuf. grid = 144, block = 256.
__global__ __launch_bounds__(256) void topk_kernel(const float* __restrict__ scg,
                                                   int* __restrict__ ibuf,
                                                   float* __restrict__ wbuf) {
  int blk = blockIdx.x;
  int tid = threadIdx.x;

  __shared__ float sc[M_];
  __shared__ unsigned hist[256];
  __shared__ int sbuf[256];
  __shared__ int selm[K_];
  __shared__ float red[256];
  __shared__ int sh_bin, sh_rem;

  const float4* srow = (const float4*)(scg + (size_t)blk * M_);
  for (int i = tid; i < M_ / 4; i += 256) ((float4*)sc)[i] = srow[i];
  __syncthreads();

  // ---- radix select: find K-th largest key ----
  unsigned prefix = 0;
  int remaining = K_;
  for (int shift = 24; shift >= 0; shift -= 8) {
    hist[tid] = 0;
    __syncthreads();
    unsigned pmask = (shift == 24) ? 0u : (0xFFFFFFFFu << (shift + 8));
    #pragma unroll 4
    for (int i = 0; i < 16; ++i) {
      unsigned k = keyf(sc[tid * 16 + i]);
      if ((k & pmask) == prefix) atomicAdd(&hist[(k >> shift) & 255u], 1u);
    }
    __syncthreads();
    int bin = 255 - tid;
    int v = (int)hist[bin];
    int cex = block_excl_scan256(v, tid, sbuf);
    if (cex < remaining && cex + v >= remaining) {
      sh_bin = bin;
      sh_rem = remaining - cex;
    }
    __syncthreads();
    prefix |= ((unsigned)sh_bin) << shift;
    remaining = sh_rem;
    __syncthreads();
  }
  const unsigned tau = prefix;
  const int r = remaining;      // # of ==tau entries to keep (lowest indices)
  const int cgt = K_ - r;       // # of >tau entries

  // ---- compact selection in ascending-index order (deterministic) ----
  int base = tid * 16;
  int myCnt = 0, myTie = 0;
  #pragma unroll
  for (int i = 0; i < 16; i++) {
    unsigned k = keyf(sc[base + i]);
    myCnt += (k > tau);
    myTie += (k == tau);
  }
  int offs = block_excl_scan256(myCnt, tid, sbuf);
  int toffs = block_excl_scan256(myTie, tid, sbuf);
  for (int i = 0; i < 16; i++) {
    int m = base + i;
    unsigned k = keyf(sc[m]);
    if (k > tau) {
      selm[offs++] = m;
    } else if (k == tau) {
      if (toffs < r) selm[cgt + toffs] = m;
      toffs++;
    }
  }
  __syncthreads();

  // ---- softmax over the K selected ----
  int m = selm[tid];
  float val = sc[m];
  red[tid] = val;
  __syncthreads();
  for (int off = 128; off > 0; off >>= 1) {
    if (tid < off) red[tid] = fmaxf(red[tid], red[tid + off]);
    __syncthreads();
  }
  float mx = red[0];
  __syncthreads();
  float e = expf(val - mx);
  red[tid] = e;
  __syncthreads();
  for (int off = 128; off > 0; off >>= 1) {
    if (tid < off) red[tid] += red[tid + off];
    __syncthreads();
  }
  ibuf[(size_t)blk * K_ + tid] = m;
  wbuf[(size_t)blk * K_ + tid] = e / red[0];
}

// wfp[blk*4+kc][c] = sum_{k in chunk} w_k * feat[m_k, c]
// grid = (144, 4, 3 c-segments), block = 256
__global__ __launch_bounds__(256) void wfeat_kernel(const float* __restrict__ x,
                                                    const int* __restrict__ ibuf,
                                                    const float* __restrict__ wbuf,
                                                    float* __restrict__ wfp) {
  int blk = blockIdx.x, kc = blockIdx.y, cseg = blockIdx.z;
  int b = blk / 36;
  int tid = threadIdx.x;
  __shared__ int ml[64];
  __shared__ float wl[64];
  if (tid < 64) {
    ml[tid] = ibuf[(size_t)blk * K_ + kc * 64 + tid];
    wl[tid] = wbuf[(size_t)blk * K_ + kc * 64 + tid];
  }
  __syncthreads();
  int c = cseg * 256 + tid;
  const float* fbase = x + ((size_t)b * TM_ + T_) * C_ + c;
  float a = 0.f;
  #pragma unroll 4
  for (int kk = 0; kk < 64; ++kk) {
    a += wl[kk] * fbase[(size_t)ml[kk] * C_];
  }
  wfp[((size_t)blk * 4 + kc) * C_ + c] = a;
}

// attn_token[b,t,h*64+rr] = (sum_kc wfp) . Wv[row] + bv[row]; grid = 144
__global__ __launch_bounds__(256) void attn_token_kernel(
    const float* __restrict__ wfp, const float* __restrict__ Wkv,
    const float* __restrict__ bkv, float* __restrict__ atbuf) {
  int blk = blockIdx.x;
  int t = blk % T_;
  int h = (blk / T_) % H_;
  int b = blk / (T_ * H_);
  int tid = threadIdx.x;
  __shared__ float wfeat[C_];
  const float* p0 = wfp + ((size_t)blk * 4) * C_;
  #pragma unroll
  for (int j = 0; j < 3; ++j) {
    int c = tid + j * 256;
    wfeat[c] = p0[c] + p0[C_ + c] + p0[2 * C_ + c] + p0[3 * C_ + c];
  }
  __syncthreads();
  int grp = tid >> 4, ln = tid & 15;
  for (int rr = grp; rr < HD_; rr += 16) {
    const float4* wr = (const float4*)(Wkv + ((size_t)(C_ + h * HD_ + rr)) * C_);
    float acc = 0.f;
    #pragma unroll
    for (int it = 0; it < 12; ++it) {
      float4 wv = wr[ln + it * 16];
      const float4 fv = *(const float4*)&wfeat[(ln + it * 16) * 4];
      acc += wv.x * fv.x + wv.y * fv.y + wv.z * fv.z + wv.w * fv.w;
    }
    acc += __shfl_xor(acc, 1, 16);
    acc += __shfl_xor(acc, 2, 16);
    acc += __shfl_xor(acc, 4, 16);
    acc += __shfl_xor(acc, 8, 16);
    if (ln == 0)
      atbuf[((size_t)(b * T_ + t)) * C_ + h * HD_ + rr] =
          acc + bkv[C_ + h * HD_ + rr];
  }
}

// token_output[b,t,d] = sum_c attn_token[b,t,c] * Wexp[t,d,c]
// grid = (T, 12 dchunks of 64), block 256. Reads Wexp once (4 b per block).
__global__ __launch_bounds__(256) void token_out(const float* __restrict__ atbuf,
                                                 const float* __restrict__ Wexp,
                                                 float* __restrict__ out) {
  int t = blockIdx.x;
  int d0 = blockIdx.y * 64;
  int tid = threadIdx.x;
  __shared__ float ar[B_][C_];
  for (int i = tid; i < B_ * C_; i += 256) {
    int bb = i / C_, c = i % C_;
    ar[bb][c] = atbuf[((size_t)(bb * T_ + t)) * C_ + c];
  }
  __syncthreads();
  int grp = tid >> 4, ln = tid & 15;
  #pragma unroll
  for (int j = 0; j < 4; ++j) {
    int d = d0 + grp * 4 + j;
    const float4* wr = (const float4*)(Wexp + ((size_t)t * C_ + d) * C_);
    float a0 = 0.f, a1 = 0.f, a2 = 0.f, a3 = 0.f;
    #pragma unroll
    for (int it = 0; it < 12; ++it) {
      float4 w4 = wr[ln + 16 * it];
      const float4 x0 = *(const float4*)&ar[0][(ln + 16 * it) * 4];
      const float4 x1 = *(const float4*)&ar[1][(ln + 16 * it) * 4];
      const float4 x2 = *(const float4*)&ar[2][(ln + 16 * it) * 4];
      const float4 x3 = *(const float4*)&ar[3][(ln + 16 * it) * 4];
      a0 += w4.x * x0.x + w4.y * x0.y + w4.z * x0.z + w4.w * x0.w;
      a1 += w4.x * x1.x + w4.y * x1.y + w4.z * x1.z + w4.w * x1.w;
      a2 += w4.x * x2.x + w4.y * x2.y + w4.z * x2.z + w4.w * x2.w;
      a3 += w4.x * x3.x + w4.y * x3.y + w4.z * x3.z + w4.w * x3.w;
    }
    #pragma unroll
    for (int off = 1; off < 16; off <<= 1) {
      a0 += __shfl_xor(a0, off, 16);
      a1 += __shfl_xor(a1, off, 16);
      a2 += __shfl_xor(a2, off, 16);
      a3 += __shfl_xor(a3, off, 16);
    }
    if (ln == 0) {
      out[((size_t)0 * TM_ + t) * C_ + d] = a0;
      out[((size_t)1 * TM_ + t) * C_ + d] = a1;
      out[((size_t)2 * TM_ + t) * C_ + d] = a2;
      out[((size_t)3 * TM_ + t) * C_ + d] = a3;
    }
  }
}

// Sparse feature expansion via MFMA GEMM per (t,h):
//   Y[64 rows][768 d] = FW[64x64 c] @ WexpT[64 c x 768 d], rows = (ks-chunk of
//   selections), then atomic-add rows into out[b, T+m, :].
// grid = (36 th, 16 rowtiles: b*4+ks), block = 256 (4 waves).
// LDS: fw bf16 [64][72] + wt bf16 [192][72] (+pad: 2-way reads = free).
__global__ __launch_bounds__(256) void scatter_mfma(
    const float* __restrict__ x, const float* __restrict__ Wexp,
    const int* __restrict__ ibuf, const float* __restrict__ wbuf,
    float* __restrict__ out) {
  int th = blockIdx.x;
  int h = th / T_, t = th % T_;
  int rt = blockIdx.y;
  int b = rt >> 2, ks = rt & 3;
  int bht = b * 36 + th;
  int tid = threadIdx.x;

  __shared__ unsigned short fw[64][72];
  __shared__ unsigned short wt[192][72];
  __shared__ int ml[64];

  if (tid < 64) ml[tid] = ibuf[(size_t)bht * K_ + ks * 64 + tid];
  // stage fw (bf16 of w * feat slice): thread = (kk, 16-c chunk)
  {
    int kk = tid >> 2, cp = (tid & 3) * 16;
    int sel = ks * 64 + kk;
    int m = ibuf[(size_t)bht * K_ + sel];
    float w = wbuf[(size_t)bht * K_ + sel];
    const float* fr = x + ((size_t)(b * TM_) + T_ + m) * C_ + h * HD_ + cp;
    float4 f0 = *(const float4*)(fr + 0);
    float4 f1 = *(const float4*)(fr + 4);
    float4 f2 = *(const float4*)(fr + 8);
    float4 f3 = *(const float4*)(fr + 12);
    uint4 u0 = make_uint4(pk2(f0.x * w, f0.y * w), pk2(f0.z * w, f0.w * w),
                          pk2(f1.x * w, f1.y * w), pk2(f1.z * w, f1.w * w));
    uint4 u1 = make_uint4(pk2(f2.x * w, f2.y * w), pk2(f2.z * w, f2.w * w),
                          pk2(f3.x * w, f3.y * w), pk2(f3.z * w, f3.w * w));
    *(uint4*)&fw[kk][cp] = u0;
    *(uint4*)&fw[kk][cp + 8] = u1;
  }
  __syncthreads();

  int lane = tid & 63, wave = tid >> 6;
  int lrow = lane & 15, lk8 = (lane >> 4) * 8, g4 = (lane >> 4) * 4;

  for (int dc = 0; dc < 4; ++dc) {
    // stage wt[dd][c] = bf16(Wexp[t, dc*192+dd, h*64+c]) — coalesced rows
    {
      #pragma unroll
      for (int r2 = 0; r2 < 3; ++r2) {
        int idx = r2 * 256 + tid;
        int dd = idx >> 2, cq = (idx & 3) * 16;
        const float* wr =
            Wexp + ((size_t)t * C_ + dc * 192 + dd) * C_ + h * HD_ + cq;
        float4 f0 = *(const float4*)(wr + 0);
        float4 f1 = *(const float4*)(wr + 4);
        float4 f2 = *(const float4*)(wr + 8);
        float4 f3 = *(const float4*)(wr + 12);
        uint4 u0 = make_uint4(pk2(f0.x, f0.y), pk2(f0.z, f0.w),
                              pk2(f1.x, f1.y), pk2(f1.z, f1.w));
        uint4 u1 = make_uint4(pk2(f2.x, f2.y), pk2(f2.z, f2.w),
                              pk2(f3.x, f3.y), pk2(f3.z, f3.w));
        *(uint4*)&wt[dd][cq] = u0;
        *(uint4*)&wt[dd][cq + 8] = u1;
      }
    }
    __syncthreads();

    f32x4 acc[12];
    #pragma unroll
    for (int n = 0; n < 12; ++n) acc[n] = (f32x4){0.f, 0.f, 0.f, 0.f};

    #pragma unroll
    for (int ks2 = 0; ks2 < 2; ++ks2) {
      bf16x8 a = *(const bf16x8*)&fw[wave * 16 + lrow][ks2 * 32 + lk8];
      #pragma unroll
      for (int n = 0; n < 12; ++n) {
        bf16x8 bfr = *(const bf16x8*)&wt[n * 16 + lrow][ks2 * 32 + lk8];
        acc[n] = __builtin_amdgcn_mfma_f32_16x16x32_bf16(a, bfr, acc[n], 0, 0, 0);
      }
    }

    // epilogue: D col = lane&15 (d), row = (lane>>4)*4 + q (local row)
    #pragma unroll
    for (int n = 0; n < 12; ++n) {
      int d = dc * 192 + n * 16 + lrow;
      #pragma unroll
      for (int q = 0; q < 4; ++q) {
        int row = wave * 16 + g4 + q;
        int mrow = ml[row];
        atomicAdd(&out[((size_t)b * TM_ + T_ + mrow) * C_ + d], acc[n][q]);
      }
    }
    __syncthreads(); // all reads of wt done before next-dc overwrite
  }
}

// ---------- launch ----------
extern "C" void kernel_launch(void* const* d_in, const int* in_sizes, int n_in,
                              void* d_out, int out_size, void* d_ws, size_t ws_size,
                              hipStream_t stream) {
  (void)in_sizes; (void)n_in; (void)ws_size;
  const float* x = (const float*)d_in[0];
  const float* Wq = (const float*)d_in[1];
  const float* bq = (const float*)d_in[2];
  const float* Wkv = (const float*)d_in[3];
  const float* bkv = (const float*)d_in[4];
  const float* Wexp = (const float*)d_in[5];
  float* out = (float*)d_out;

  // workspace layout (~14.4 MiB used)
  char* ws = (char*)d_ws;
  float* qbuf = (float*)ws;                          //        36,864 B
  float* atbuf = (float*)(ws + 36864);               //        36,864 B
  int* ibuf = (int*)(ws + 73728);                    //       147,456 B
  float* wbuf = (float*)(ws + 221184);               //       147,456 B
  float* sprjT = (float*)(ws + 368640);              //       442,368 B
  float* qbb = (float*)(ws + 811008);                //     1,024 B pad
  float* scg = (float*)(ws + 812032);                //     2,359,296 B
  float* scp = (float*)(ws + 3171328);               //     9,437,184 B
  float* wfp = (float*)(ws + 12608512);              //     1,769,472 B

  int n4 = out_size / 4;
  zero_out_kernel<<<(n4 + 255) / 256, 256, 0, stream>>>((float4*)out, n4);
  q_kernel<<<dim3(T_, 12), 256, 0, stream>>>(x, Wq, bq, qbuf);
  sprj_kernel<<<NBLK_, 256, 0, stream>>>(qbuf, Wkv, bkv, sprjT, qbb);
  score_kernel<<<dim3(B_, 16, 4), 256, 0, stream>>>(x, sprjT, scp);
  score_reduce<<<dim3(NBLK_, 4), 256, 0, stream>>>(scp, qbb, scg);
  topk_kernel<<<NBLK_, 256, 0, stream>>>(scg, ibuf, wbuf);
  wfeat_kernel<<<dim3(NBLK_, 4, 3), 256, 0, stream>>>(x, ibuf, wbuf, wfp);
  attn_token_kernel<<<NBLK_, 256, 0, stream>>>(wfp, Wkv, bkv, atbuf);
  token_out<<<dim3(T_, 12), 256, 0, stream>>>(atbuf, Wexp, out);
  scatter_mfma<<<dim3(36, 16), 256, 0, stream>>>(x, Wexp, ibuf, wbuf, out);
}